// Round 11
// baseline (352.212 us; speedup 1.0000x reference)
//
#include <hip/hip_runtime.h>
#include <hip/hip_fp16.h>
#include <stdint.h>

// ---------------- problem constants ----------------
#define NODES 50000
#define F_IN 128
#define F_H1 256
#define F_H2 256
#define F_OUT 64
#define SLICES 64            // edge slices for hist/scatter
#define NPACK (NODES / 2)    // packed ushort-pair bins (25000)
#define QPACK (NPACK / 4)    // bins per node-quarter (6250, 25 KB LDS per array)

using f32x4    = __attribute__((ext_vector_type(4))) float;
using f16x8    = __attribute__((ext_vector_type(8))) _Float16;   // 8 fp16 in 4 VGPRs
using ushort8v = __attribute__((ext_vector_type(8))) unsigned short;

// ---------------- atomic-free degree/CSR machinery ----------------
__global__ __launch_bounds__(512) void k_hist2(
    const int* __restrict__ src, const int* __restrict__ dst,
    unsigned* __restrict__ p_out, unsigned* __restrict__ p_in, int e) {
  __shared__ unsigned bo[QPACK];
  __shared__ unsigned bi[QPACK];
  const int s = blockIdx.x >> 2;
  const int r = blockIdx.x & 3;
  const int nlo = r * (NODES / 4);
  const int nhi = nlo + NODES / 4;
  const int plo = r * QPACK;
  const int per = (e + SLICES - 1) / SLICES;
  const int beg = s * per;
  const int end = min(e, beg + per);

  for (int j = threadIdx.x; j < QPACK; j += 512) { bo[j] = 0; bi[j] = 0; }
  __syncthreads();
  for (int i = beg + (int)threadIdx.x; i < end; i += 512) {
    int a = src[i];
    if (a >= nlo && a < nhi)
      atomicAdd(&bo[(a >> 1) - plo], 1u << ((a & 1) << 4));
    int d = dst[i];
    if (d >= nlo && d < nhi)
      atomicAdd(&bi[(d >> 1) - plo], 1u << ((d & 1) << 4));
  }
  __syncthreads();
  for (int j = threadIdx.x; j < QPACK; j += 512) {
    p_out[(size_t)s * NPACK + plo + j] = bo[j];
    p_in[(size_t)s * NPACK + plo + j] = bi[j];
  }
}

__global__ __launch_bounds__(256) void k_degnorm(
    const unsigned* __restrict__ p_out, const unsigned* __restrict__ p_in,
    unsigned* __restrict__ base_in, int* __restrict__ deg_in,
    float* __restrict__ ns, float* __restrict__ nd) {
  int p = blockIdx.x * 256 + threadIdx.x;
  if (p >= NPACK) return;
  unsigned so = 0, si = 0;
#pragma unroll 4
  for (int s = 0; s < SLICES; ++s) {
    so += p_out[(size_t)s * NPACK + p];
    unsigned vi = p_in[(size_t)s * NPACK + p];
    base_in[(size_t)s * NPACK + p] = si;   // exclusive prefix across slices
    si += vi;
  }
  int o0 = (int)(so & 0xFFFFu) + 1, o1 = (int)(so >> 16) + 1;   // +1 self-loop
  int i0 = (int)(si & 0xFFFFu) + 1, i1 = (int)(si >> 16) + 1;
  int n0 = p * 2, n1 = n0 + 1;
  deg_in[n0] = i0; deg_in[n1] = i1;
  ns[n0] = rsqrtf((float)o0); ns[n1] = rsqrtf((float)o1);
  nd[n0] = rsqrtf((float)i0); nd[n1] = rsqrtf((float)i1);
}

// ---------------- parallel 3-phase exclusive scan over (deg_in - 1) ----------------
__global__ __launch_bounds__(256) void k_scan1(const int* __restrict__ deg_in,
                                               int* __restrict__ psum, int n) {
  int i = blockIdx.x * 256 + threadIdx.x;
  int v = (i < n) ? deg_in[i] - 1 : 0;
#pragma unroll
  for (int o = 1; o < 64; o <<= 1) v += __shfl_xor(v, o);
  __shared__ int ws[4];
  if ((threadIdx.x & 63) == 0) ws[threadIdx.x >> 6] = v;
  __syncthreads();
  if (threadIdx.x == 0) psum[blockIdx.x] = ws[0] + ws[1] + ws[2] + ws[3];
}

__global__ __launch_bounds__(256) void k_scan2(int* __restrict__ psum, int nb) {
  __shared__ int s[256];
  int t = threadIdx.x;
  int v = (t < nb) ? psum[t] : 0;
  s[t] = v;
  __syncthreads();
  for (int o = 1; o < 256; o <<= 1) {
    int u = (t >= o) ? s[t - o] : 0;
    __syncthreads();
    s[t] += u;
    __syncthreads();
  }
  if (t < nb) psum[t] = s[t] - v;   // exclusive
}

__global__ __launch_bounds__(256) void k_scan3(const int* __restrict__ deg_in,
                                               const int* __restrict__ psum,
                                               int* __restrict__ row_ptr, int n) {
  int i = blockIdx.x * 256 + threadIdx.x;
  int lane = threadIdx.x & 63;
  int w = threadIdx.x >> 6;
  int v = (i < n) ? deg_in[i] - 1 : 0;
  int x = v;
#pragma unroll
  for (int o = 1; o < 64; o <<= 1) {
    int u = __shfl_up(x, o);
    if (lane >= o) x += u;
  }
  __shared__ int wsum[4];
  if (lane == 63) wsum[w] = x;
  __syncthreads();
  int woff = 0;
#pragma unroll
  for (int j = 0; j < 4; ++j)
    if (j < w) woff += wsum[j];
  int excl = x - v + woff + psum[blockIdx.x];
  if (i < n) row_ptr[i] = excl;
  if (i == n - 1) row_ptr[n] = excl + v;
}

__global__ __launch_bounds__(512) void k_scatter4(
    const int* __restrict__ src, const int* __restrict__ dst,
    const int* __restrict__ row_ptr, const unsigned* __restrict__ base_in,
    int* __restrict__ csr_src, int e) {
  __shared__ unsigned cur[QPACK];
  const int s = blockIdx.x >> 2;
  const int r = blockIdx.x & 3;
  const int nlo = r * (NODES / 4);
  const int nhi = nlo + NODES / 4;
  const int plo = r * QPACK;
  const int per = (e + SLICES - 1) / SLICES;
  const int beg = s * per;
  const int end = min(e, beg + per);
  for (int j = threadIdx.x; j < QPACK; j += 512)
    cur[j] = base_in[(size_t)s * NPACK + plo + j];
  __syncthreads();
  for (int i = beg + (int)threadIdx.x; i < end; i += 512) {
    int d = dst[i];
    if (d >= nlo && d < nhi) {
      int sh = (d & 1) << 4;
      unsigned old = atomicAdd(&cur[(d >> 1) - plo], 1u << sh);
      int local = (int)((old >> sh) & 0xFFFFu);
      csr_src[row_ptr[d] + local] = src[i];
    }
  }
}

// ---------------- feats prescale -> fp16: Y = fp16(ns[row] * X), X:[n][128] ----------------
__global__ void k_prescale_h(const float* __restrict__ X, const float* __restrict__ ns,
                             __half* __restrict__ Y, int total4) {
  int i = blockIdx.x * blockDim.x + threadIdx.x;
  if (i < total4) {
    int row = i >> 5;                       // 32 float4 per 128-col row
    float s = ns[row];
    float4 v = reinterpret_cast<const float4*>(X)[i];
    __half2 h0 = __floats2half2_rn(v.x * s, v.y * s);
    __half2 h1 = __floats2half2_rn(v.z * s, v.w * s);
    union { struct { __half2 a, b; } h; uint2 u; } o;
    o.h.a = h0; o.h.b = h1;
    reinterpret_cast<uint2*>(Y)[i] = o.u;
  }
}

// ---------------- weight prep (all three in one launch): W[K][NOUT] -> Wt[NOUT][K] fp16 ----
__global__ void k_wprep_all(const float* __restrict__ W1, const float* __restrict__ W2,
                            const float* __restrict__ W3, __half* __restrict__ wt1,
                            __half* __restrict__ wt2, __half* __restrict__ wt3) {
  int i = blockIdx.x * 256 + threadIdx.x;
  if (i < F_IN * F_H1) {
    int k = i >> 8, n = i & 255;
    wt1[(size_t)n * F_IN + k] = __float2half_rn(W1[i]);
  } else if (i < F_IN * F_H1 + F_H1 * F_H2) {
    int j = i - F_IN * F_H1;
    int k = j >> 8, n = j & 255;
    wt2[(size_t)n * F_H1 + k] = __float2half_rn(W2[j]);
  } else if (i < F_IN * F_H1 + F_H1 * F_H2 + F_H2 * F_OUT) {
    int j = i - F_IN * F_H1 - F_H1 * F_H2;
    int k = j >> 6, n = j & 63;
    wt3[(size_t)n * F_H2 + k] = __float2half_rn(W3[j]);
  }
}

// ---------------- fp16 gather helpers ----------------
struct u32x8s { uint4 a, b; };
template <int HPL> struct raw_t_sel;
template <> struct raw_t_sel<2> { using type = unsigned int; };
template <> struct raw_t_sel<4> { using type = uint2; };
template <> struct raw_t_sel<8> { using type = uint4; };
template <> struct raw_t_sel<16> { using type = u32x8s; };

template <int HPL>
__device__ __forceinline__ typename raw_t_sel<HPL>::type graw(const __half* p) {
  if constexpr (HPL == 16) {
    u32x8s r;
    r.a = *reinterpret_cast<const uint4*>(p);
    r.b = *reinterpret_cast<const uint4*>(p + 8);
    return r;
  } else {
    return *reinterpret_cast<const typename raw_t_sel<HPL>::type*>(p);
  }
}
__device__ __forceinline__ void acc_u32(float* acc, unsigned u) {
  union { unsigned u; __half2 h; } a; a.u = u;
  float2 f = __half22float2(a.h);
  acc[0] += f.x; acc[1] += f.y;
}
template <int HPL>
__device__ __forceinline__ void raw_acc(float* acc, typename raw_t_sel<HPL>::type r) {
  if constexpr (HPL == 16) {
    acc_u32(acc + 0, r.a.x);  acc_u32(acc + 2, r.a.y);
    acc_u32(acc + 4, r.a.z);  acc_u32(acc + 6, r.a.w);
    acc_u32(acc + 8, r.b.x);  acc_u32(acc + 10, r.b.y);
    acc_u32(acc + 12, r.b.z); acc_u32(acc + 14, r.b.w);
  } else if constexpr (HPL == 8) {
    acc_u32(acc + 0, r.x); acc_u32(acc + 2, r.y);
    acc_u32(acc + 4, r.z); acc_u32(acc + 6, r.w);
  } else if constexpr (HPL == 4) {
    acc_u32(acc + 0, r.x); acc_u32(acc + 2, r.y);
  } else {
    acc_u32(acc, r);
  }
}

// ---------------- fused SpMM + GEMM (layers 1 & 2) ----------------
// Per block: 64 output rows. Phase 1: gather-aggregate rows of X (d=K) into
// LDS As (fp16, nd-scaled). Phase 2: MFMA GEMM K->256 with W staged per
// 32-K step; bias + relu + *ns epilogue, fp16 C out. Blocks overlap phases
// across the CU -> GEMM time hides under the gather memory wall.
template <int K>
__global__ __launch_bounds__(256) void k_fused(
    const __half* __restrict__ X, const int* __restrict__ row_ptr,
    const int* __restrict__ csr_src, const float* __restrict__ nd,
    const __half* __restrict__ Wt, const float* __restrict__ bias,
    const float* __restrict__ ns, __half* __restrict__ C, int M) {
  constexpr int BN = 256;
  constexpr int LPN = K / 16;     // lanes per row (32 B each): 16 (K=256) / 8 (K=128)
  constexpr int EPI = 64 / LPN;   // edges per wave-iteration: 4 / 8
  constexpr int LDPA = K + 8;     // 16B-aligned row stride
  constexpr int LDPB = 40;

  __shared__ __half As[64][LDPA];
  __shared__ __half Ws[BN][LDPB];

  const int tid = threadIdx.x;
  const int bm = blockIdx.x * 64;
  const int lane = tid & 63;
  const int wave = tid >> 6;      // 0..3
  const int sub = lane / LPN;     // edge slot
  const int fl = lane % LPN;      // feature lane
  const int off = fl * 16;        // halves offset (32 B per lane)

  // ---- phase 1: each wave gathers 16 rows ----
  for (int t = 0; t < 16; ++t) {
    const int r = wave * 16 + t;
    const int v = bm + r;
    float acc[16] = {};
    if (v < M) {
      const __half* __restrict__ Xo = X + off;
      if (sub == 0) raw_acc<16>(acc, graw<16>(Xo + (size_t)v * K));   // self term
      const int beg = row_ptr[v];
      const int end = row_ptr[v + 1];
#pragma unroll 2
      for (int e = beg + sub; e < end; e += EPI)
        raw_acc<16>(acc, graw<16>(Xo + (size_t)csr_src[e] * K));
    }
#pragma unroll
    for (int o = LPN; o < 64; o <<= 1)
#pragma unroll
      for (int i = 0; i < 16; ++i) acc[i] += __shfl_xor(acc[i], o);
    if (sub == 0) {
      const float sc = (v < M) ? nd[v] : 0.f;
      union { struct { __half2 a, b, c, d; } h; uint4 u; } p0, p1;
      p0.h.a = __floats2half2_rn(sc * acc[0], sc * acc[1]);
      p0.h.b = __floats2half2_rn(sc * acc[2], sc * acc[3]);
      p0.h.c = __floats2half2_rn(sc * acc[4], sc * acc[5]);
      p0.h.d = __floats2half2_rn(sc * acc[6], sc * acc[7]);
      p1.h.a = __floats2half2_rn(sc * acc[8], sc * acc[9]);
      p1.h.b = __floats2half2_rn(sc * acc[10], sc * acc[11]);
      p1.h.c = __floats2half2_rn(sc * acc[12], sc * acc[13]);
      p1.h.d = __floats2half2_rn(sc * acc[14], sc * acc[15]);
      *reinterpret_cast<uint4*>(&As[r][off]) = p0.u;
      *reinterpret_cast<uint4*>(&As[r][off + 8]) = p1.u;
    }
  }
  __syncthreads();

  // ---- phase 2: GEMM K->256, A from persistent LDS tile ----
  const int wni = wave;           // 4 waves across N (64 cols each)
  const int rl = lane & 15;
  const int kg = lane >> 4;
  const int kb = kg * 8;

  f32x4 acc2[4][4];
#pragma unroll
  for (int m = 0; m < 4; ++m)
#pragma unroll
    for (int n = 0; n < 4; ++n) acc2[m][n] = (f32x4){0.f, 0.f, 0.f, 0.f};

  for (int kk = 0; kk < K; kk += 32) {
#pragma unroll
    for (int s0 = 0; s0 < BN * 4; s0 += 256) {
      int s = s0 + tid;
      int nn = s >> 2, k8 = (s & 3) << 3;
      *reinterpret_cast<ushort8v*>(&Ws[nn][k8]) =
          *reinterpret_cast<const ushort8v*>(Wt + (size_t)nn * K + kk + k8);
    }
    __syncthreads();

    f16x8 af[4], bf[4];
#pragma unroll
    for (int m = 0; m < 4; ++m)
      af[m] = *reinterpret_cast<const f16x8*>(&As[m * 16 + rl][kk + kb]);
#pragma unroll
    for (int n = 0; n < 4; ++n)
      bf[n] = *reinterpret_cast<const f16x8*>(&Ws[wni * 64 + n * 16 + rl][kb]);
#pragma unroll
    for (int m = 0; m < 4; ++m)
#pragma unroll
      for (int n = 0; n < 4; ++n)
        acc2[m][n] = __builtin_amdgcn_mfma_f32_16x16x32_f16(af[m], bf[n], acc2[m][n], 0, 0, 0);
    __syncthreads();
  }

  // ---- epilogue: + bias, relu, * ns[row], fp16 store ----
#pragma unroll
  for (int m = 0; m < 4; ++m) {
#pragma unroll
    for (int n = 0; n < 4; ++n) {
      const int col = wni * 64 + n * 16 + rl;
      const float bb = bias[col];
      const int rowbase = bm + m * 16 + kg * 4;
#pragma unroll
      for (int i = 0; i < 4; ++i) {
        int grow = rowbase + i;
        if (grow < M) {
          float val = fmaxf(acc2[m][n][i] + bb, 0.f) * ns[grow];
          C[(size_t)grow * BN + col] = __float2half_rn(val);
        }
      }
    }
  }
}

// ---------------- standalone SpMM (layer 3 tail): d=64, f32 out ----------------
template <int D, int EPI, bool BIAS, bool OHALF>
__global__ __launch_bounds__(256) void k_spmm_h(
    const __half* __restrict__ X, const int* __restrict__ row_ptr,
    const int* __restrict__ csr_src, const float* __restrict__ nd,
    const float* __restrict__ bias, void* __restrict__ Y, int n) {
  constexpr int LPN = 64 / EPI;    // lanes per edge-row
  constexpr int HPL = D / LPN;     // halves per lane
  static_assert(HPL >= 2 && HPL <= 16, "bad HPL");
  const int v = (blockIdx.x * blockDim.x + threadIdx.x) >> 6;
  const int lane = threadIdx.x & 63;
  if (v >= n) return;
  const int sub = lane / LPN;
  const int fl = lane % LPN;
  const int off = fl * HPL;
  const __half* __restrict__ Xo = X + off;

  float acc[HPL] = {};
  if (sub == 0) raw_acc<HPL>(acc, graw<HPL>(Xo + (size_t)v * D));   // self term

  const int beg = row_ptr[v];
  const int end = row_ptr[v + 1];
#pragma unroll 2
  for (int e = beg + sub; e < end; e += EPI) {
    int u = csr_src[e];
    raw_acc<HPL>(acc, graw<HPL>(Xo + (size_t)u * D));
  }

#pragma unroll
  for (int o = LPN; o < 64; o <<= 1)
#pragma unroll
    for (int i = 0; i < HPL; ++i) acc[i] += __shfl_xor(acc[i], o);

  if (sub != 0) return;
  const float sc = nd[v];
  float o[HPL];
#pragma unroll
  for (int i = 0; i < HPL; ++i) {
    o[i] = sc * acc[i];
    if (BIAS) o[i] += bias[off + i];
  }

  if constexpr (OHALF) {
    __half* yp = reinterpret_cast<__half*>(Y) + (size_t)v * D + off;
    if constexpr (HPL == 8) {
      union { struct { __half2 a, b, c, d; } h; uint4 u; } pk;
      pk.h.a = __floats2half2_rn(o[0], o[1]);
      pk.h.b = __floats2half2_rn(o[2], o[3]);
      pk.h.c = __floats2half2_rn(o[4], o[5]);
      pk.h.d = __floats2half2_rn(o[6], o[7]);
      *reinterpret_cast<uint4*>(yp) = pk.u;
    } else if constexpr (HPL == 4) {
      union { struct { __half2 a, b; } h; uint2 u; } pk;
      pk.h.a = __floats2half2_rn(o[0], o[1]);
      pk.h.b = __floats2half2_rn(o[2], o[3]);
      *reinterpret_cast<uint2*>(yp) = pk.u;
    } else {
      *reinterpret_cast<__half2*>(yp) = __floats2half2_rn(o[0], o[1]);
    }
  } else {
    float* yp = reinterpret_cast<float*>(Y) + (size_t)v * D + off;
    if constexpr (HPL == 8) {
      *reinterpret_cast<float4*>(yp) = make_float4(o[0], o[1], o[2], o[3]);
      *reinterpret_cast<float4*>(yp + 4) = make_float4(o[4], o[5], o[6], o[7]);
    } else if constexpr (HPL == 4) {
      *reinterpret_cast<float4*>(yp) = make_float4(o[0], o[1], o[2], o[3]);
    } else {
      *reinterpret_cast<float2*>(yp) = make_float2(o[0], o[1]);
    }
  }
}

// ---------------- pure-fp16 MFMA GEMM (layer 3 head: 256 -> 64) ----------------
template <int K, int NOUT, int BM, int WM, int WN, int MF, int NF,
          bool RELU, bool BIAS, bool NSOUT, bool OHALF>
__global__ __launch_bounds__(256) void k_gemm_h(
    const __half* __restrict__ A, const __half* __restrict__ Wt,
    const float* __restrict__ bias, const float* __restrict__ ns,
    void* __restrict__ C, int M) {
  constexpr int BN = WN * NF * 16;
  static_assert(BM == WM * MF * 16, "BM mismatch");
  static_assert(BN == NOUT, "BN must equal NOUT");
  constexpr int LDP = 40;

  __shared__ __half As[BM][LDP];
  __shared__ __half Ws[BN][LDP];

  const int tid = threadIdx.x;
  const int bm = blockIdx.x * BM;
  const int lane = tid & 63;
  const int wave = tid >> 6;
  const int wmi = wave / WN;
  const int wni = wave % WN;
  const int rl = lane & 15;
  const int kg = lane >> 4;
  const int kb = kg * 8;

  f32x4 acc[MF][NF];
#pragma unroll
  for (int m = 0; m < MF; ++m)
#pragma unroll
    for (int n = 0; n < NF; ++n) acc[m][n] = (f32x4){0.f, 0.f, 0.f, 0.f};

  for (int kk = 0; kk < K; kk += 32) {
#pragma unroll
    for (int s0 = 0; s0 < BM * 4; s0 += 256) {
      int s = s0 + tid;
      int r = s >> 2, c8 = (s & 3) << 3;
      int grow = bm + r;
      ushort8v v = (ushort8v){0, 0, 0, 0, 0, 0, 0, 0};
      if (grow < M)
        v = *reinterpret_cast<const ushort8v*>(A + (size_t)grow * K + kk + c8);
      *reinterpret_cast<ushort8v*>(&As[r][c8]) = v;
    }
#pragma unroll
    for (int s0 = 0; s0 < BN * 4; s0 += 256) {
      int s = s0 + tid;
      int nn = s >> 2, k8 = (s & 3) << 3;
      *reinterpret_cast<ushort8v*>(&Ws[nn][k8]) =
          *reinterpret_cast<const ushort8v*>(Wt + (size_t)nn * K + kk + k8);
    }
    __syncthreads();

    f16x8 af[MF], bf[NF];
#pragma unroll
    for (int m = 0; m < MF; ++m) {
      const int r = wmi * MF * 16 + m * 16 + rl;
      af[m] = *reinterpret_cast<const f16x8*>(&As[r][kb]);
    }
#pragma unroll
    for (int n = 0; n < NF; ++n) {
      const int c = wni * NF * 16 + n * 16 + rl;
      bf[n] = *reinterpret_cast<const f16x8*>(&Ws[c][kb]);
    }
#pragma unroll
    for (int m = 0; m < MF; ++m)
#pragma unroll
      for (int n = 0; n < NF; ++n)
        acc[m][n] = __builtin_amdgcn_mfma_f32_16x16x32_f16(af[m], bf[n], acc[m][n], 0, 0, 0);
    __syncthreads();
  }

#pragma unroll
  for (int m = 0; m < MF; ++m) {
#pragma unroll
    for (int n = 0; n < NF; ++n) {
      const int col = wni * NF * 16 + n * 16 + rl;
      const float bb = BIAS ? bias[col] : 0.f;
      const int rowbase = bm + wmi * MF * 16 + m * 16 + kg * 4;
#pragma unroll
      for (int i = 0; i < 4; ++i) {
        int grow = rowbase + i;
        if (grow < M) {
          float val = acc[m][n][i] + bb;
          if (RELU) val = fmaxf(val, 0.f);
          if (NSOUT) val *= ns[grow];
          if constexpr (OHALF)
            reinterpret_cast<__half*>(C)[(size_t)grow * NOUT + col] = __float2half_rn(val);
          else
            reinterpret_cast<float*>(C)[(size_t)grow * NOUT + col] = val;
        }
      }
    }
  }
}

// ---------------- launch ----------------
extern "C" void kernel_launch(void* const* d_in, const int* in_sizes, int n_in,
                              void* d_out, int out_size, void* d_ws, size_t ws_size,
                              hipStream_t stream) {
  const float* feats = (const float*)d_in[0];
  const float* W1 = (const float*)d_in[1];
  const float* b1 = (const float*)d_in[2];
  const float* W2 = (const float*)d_in[3];
  const float* b2 = (const float*)d_in[4];
  const float* W3 = (const float*)d_in[5];
  const float* b3 = (const float*)d_in[6];
  const int* src = (const int*)d_in[7];
  const int* dst = (const int*)d_in[8];
  float* out = (float*)d_out;
  const int N = NODES;
  const int E = in_sizes[7];
  const int NB = (N + 255) / 256;          // scan blocks (196 <= 256)

  char* ws = (char*)d_ws;
  size_t off = 0;
  auto alloc = [&](size_t bytes) -> void* {
    void* p = ws + off;
    off += (bytes + 255) & ~(size_t)255;
    return p;
  };
  __half* w0h = (__half*)alloc((size_t)N * 256 * sizeof(__half));  // layer2 out
  __half* w1r = (__half*)alloc((size_t)N * 256 * sizeof(__half));  // layer1 out
  __half* w2r = (__half*)alloc((size_t)N * 256 * sizeof(__half));  // prescaled feats -> gemm3 out
  int* deg_in = (int*)alloc((size_t)N * sizeof(int));
  float* ns = (float*)alloc((size_t)N * sizeof(float));
  float* nd = (float*)alloc((size_t)N * sizeof(float));
  int* row_ptr = (int*)alloc((size_t)(N + 1) * sizeof(int));
  int* csr_src = (int*)alloc((size_t)E * sizeof(int));
  int* psum = (int*)alloc((size_t)NB * sizeof(int));
  unsigned* p_out = (unsigned*)alloc((size_t)SLICES * NPACK * sizeof(unsigned));
  unsigned* p_in = (unsigned*)alloc((size_t)SLICES * NPACK * sizeof(unsigned));
  unsigned* base_in = (unsigned*)alloc((size_t)SLICES * NPACK * sizeof(unsigned));
  __half* wt1 = (__half*)alloc((size_t)F_IN * F_H1 * sizeof(__half));
  __half* wt2 = (__half*)alloc((size_t)F_H1 * F_H2 * sizeof(__half));
  __half* wt3 = (__half*)alloc((size_t)F_H2 * F_OUT * sizeof(__half));
  (void)ws_size; (void)n_in; (void)out_size;

  // ---- weight transpose -> fp16 (single launch) ----
  const int WPTOT = F_IN * F_H1 + F_H1 * F_H2 + F_H2 * F_OUT;
  hipLaunchKernelGGL(k_wprep_all, dim3((WPTOT + 255) / 256), dim3(256), 0, stream,
                     W1, W2, W3, wt1, wt2, wt3);

  // ---- graph preprocessing (no global atomics) ----
  hipLaunchKernelGGL(k_hist2, dim3(SLICES * 4), dim3(512), 0, stream,
                     src, dst, p_out, p_in, E);
  hipLaunchKernelGGL(k_degnorm, dim3((NPACK + 255) / 256), dim3(256), 0, stream,
                     p_out, p_in, base_in, deg_in, ns, nd);
  hipLaunchKernelGGL(k_scan1, dim3(NB), dim3(256), 0, stream, deg_in, psum, N);
  hipLaunchKernelGGL(k_scan2, dim3(1), dim3(256), 0, stream, psum, NB);
  hipLaunchKernelGGL(k_scan3, dim3(NB), dim3(256), 0, stream, deg_in, psum, row_ptr, N);
  hipLaunchKernelGGL(k_scatter4, dim3(SLICES * 4), dim3(512), 0, stream,
                     src, dst, row_ptr, base_in, csr_src, E);

  // ---- prescale feats by ns -> fp16 ----
  hipLaunchKernelGGL(k_prescale_h, dim3((N * 32 + 255) / 256), dim3(256), 0, stream,
                     feats, ns, w2r, N * 32);

  // ---- layer 1 fused: gather(d=128) + GEMM 128->256 (+b1, relu, *ns) -> fp16 ----
  hipLaunchKernelGGL((k_fused<128>), dim3((N + 63) / 64), dim3(256), 0, stream,
                     w2r, row_ptr, csr_src, nd, wt1, b1, ns, w1r, N);

  // ---- layer 2 fused: gather(d=256) + GEMM 256->256 (+b2, relu, *ns) -> fp16 ----
  hipLaunchKernelGGL((k_fused<256>), dim3((N + 63) / 64), dim3(256), 0, stream,
                     w1r, row_ptr, csr_src, nd, wt2, b2, ns, w0h, N);

  // ---- layer 3: GEMM 256->64 (no act) -> fp16; SpMM(d=64, EPI=8) +b3 -> out f32 ----
  hipLaunchKernelGGL((k_gemm_h<256, 64, 128, 4, 1, 2, 4, false, false, false, true>),
                     dim3((N + 127) / 128), dim3(256), 0, stream,
                     w0h, wt3, nullptr, nullptr, w2r, N);
  hipLaunchKernelGGL((k_spmm_h<64, 8, true, false>), dim3((N + 3) / 4), dim3(256), 0, stream,
                     w2r, row_ptr, csr_src, nd, b3, out, N);
}

// Round 12
// 282.320 us; speedup vs baseline: 1.2476x; 1.2476x over previous
//
#include <hip/hip_runtime.h>
#include <hip/hip_fp16.h>
#include <hip/hip_cooperative_groups.h>
#include <stdint.h>

namespace cg = cooperative_groups;

// ---------------- problem constants ----------------
#define NODES 50000
#define F_IN 128
#define F_H1 256
#define F_H2 256
#define F_OUT 64
#define SLICES 64            // edge slices for hist/scatter
#define NPACK (NODES / 2)    // packed ushort-pair bins (25000)
#define QPACK (NPACK / 4)    // bins per node-quarter (6250, 25 KB LDS per array)
#define META_B 196           // csrmeta blocks: 196*256 >= NODES, 196*128 >= NPACK

using f32x4    = __attribute__((ext_vector_type(4))) float;
using f16x8    = __attribute__((ext_vector_type(8))) _Float16;   // 8 fp16 in 4 VGPRs
using ushort8v = __attribute__((ext_vector_type(8))) unsigned short;

// ---------------- atomic-free degree/CSR machinery ----------------
__global__ __launch_bounds__(512) void k_hist2(
    const int* __restrict__ src, const int* __restrict__ dst,
    unsigned* __restrict__ p_out, unsigned* __restrict__ p_in, int e) {
  __shared__ unsigned bo[QPACK];
  __shared__ unsigned bi[QPACK];
  const int s = blockIdx.x >> 2;
  const int r = blockIdx.x & 3;
  const int nlo = r * (NODES / 4);
  const int nhi = nlo + NODES / 4;
  const int plo = r * QPACK;
  const int per = (e + SLICES - 1) / SLICES;
  const int beg = s * per;
  const int end = min(e, beg + per);

  for (int j = threadIdx.x; j < QPACK; j += 512) { bo[j] = 0; bi[j] = 0; }
  __syncthreads();
  for (int i = beg + (int)threadIdx.x; i < end; i += 512) {
    int a = src[i];
    if (a >= nlo && a < nhi)
      atomicAdd(&bo[(a >> 1) - plo], 1u << ((a & 1) << 4));
    int d = dst[i];
    if (d >= nlo && d < nhi)
      atomicAdd(&bi[(d >> 1) - plo], 1u << ((d & 1) << 4));
  }
  __syncthreads();
  for (int j = threadIdx.x; j < QPACK; j += 512) {
    p_out[(size_t)s * NPACK + plo + j] = bo[j];
    p_in[(size_t)s * NPACK + plo + j] = bi[j];
  }
}

// k_csrmeta (cooperative): degnorm + scan1 + scan2 + scan3 in one kernel.
// Block b owns packed bins [b*128, b*128+128) == nodes [b*256, b*256+256).
// Phase A: reduce slice partials -> norms, base_in, deg-1 (LDS). Block sum -> psum[b].
// grid.sync. Phase B: each block sums psum[0..b-1]. Phase C: in-block node scan -> row_ptr.
__global__ __launch_bounds__(256) void k_csrmeta(
    const unsigned* __restrict__ p_out, const unsigned* __restrict__ p_in,
    unsigned* __restrict__ base_in, float* __restrict__ ns, float* __restrict__ nd,
    int* __restrict__ psum, int* __restrict__ row_ptr) {
  const int b = blockIdx.x;
  const int t = threadIdx.x;
  const int lane = t & 63;
  const int w = t >> 6;
  __shared__ int degm1[256];
  __shared__ int wsum[4];
  __shared__ int bsum[4];

  // ---- phase A ----
  int d0 = 0, d1 = 0;
  if (t < 128) {
    int p = b * 128 + t;
    if (p < NPACK) {
      unsigned so = 0, si = 0;
#pragma unroll 4
      for (int s = 0; s < SLICES; ++s) {
        so += p_out[(size_t)s * NPACK + p];
        unsigned vi = p_in[(size_t)s * NPACK + p];
        base_in[(size_t)s * NPACK + p] = si;   // exclusive prefix across slices
        si += vi;
      }
      int o0 = (int)(so & 0xFFFFu) + 1, o1 = (int)(so >> 16) + 1;   // +1 self-loop
      int i0 = (int)(si & 0xFFFFu) + 1, i1 = (int)(si >> 16) + 1;
      int n0 = p * 2, n1 = n0 + 1;
      ns[n0] = rsqrtf((float)o0); ns[n1] = rsqrtf((float)o1);
      nd[n0] = rsqrtf((float)i0); nd[n1] = rsqrtf((float)i1);
      d0 = i0 - 1; d1 = i1 - 1;
    }
    degm1[2 * t] = d0;
    degm1[2 * t + 1] = d1;
  }
  __syncthreads();

  const int v = degm1[t];
  int x = v;
#pragma unroll
  for (int o = 1; o < 64; o <<= 1) {
    int u = __shfl_up(x, o);
    if (lane >= o) x += u;
  }
  if (lane == 63) wsum[w] = x;
  __syncthreads();
  if (t == 0) psum[b] = wsum[0] + wsum[1] + wsum[2] + wsum[3];

  cg::this_grid().sync();

  // ---- phase B: prefix over blocks (gridDim <= 256) ----
  int pv = (t < b) ? psum[t] : 0;
#pragma unroll
  for (int o = 1; o < 64; o <<= 1) pv += __shfl_xor(pv, o);
  if (lane == 0) bsum[w] = pv;
  __syncthreads();
  const int prefix = bsum[0] + bsum[1] + bsum[2] + bsum[3];

  // ---- phase C: row_ptr ----
  int woff = 0;
#pragma unroll
  for (int j = 0; j < 4; ++j)
    if (j < w) woff += wsum[j];
  const int excl = (x - v) + woff + prefix;
  const int node = b * 256 + t;
  if (node < NODES) row_ptr[node] = excl;
  if (node == NODES - 1) row_ptr[NODES] = excl + v;
}

// k_scatter4: counting-sort scatter, zero global atomics; quarter-node blocks.
__global__ __launch_bounds__(512) void k_scatter4(
    const int* __restrict__ src, const int* __restrict__ dst,
    const int* __restrict__ row_ptr, const unsigned* __restrict__ base_in,
    int* __restrict__ csr_src, int e) {
  __shared__ unsigned cur[QPACK];
  const int s = blockIdx.x >> 2;
  const int r = blockIdx.x & 3;
  const int nlo = r * (NODES / 4);
  const int nhi = nlo + NODES / 4;
  const int plo = r * QPACK;
  const int per = (e + SLICES - 1) / SLICES;
  const int beg = s * per;
  const int end = min(e, beg + per);
  for (int j = threadIdx.x; j < QPACK; j += 512)
    cur[j] = base_in[(size_t)s * NPACK + plo + j];
  __syncthreads();
  for (int i = beg + (int)threadIdx.x; i < end; i += 512) {
    int d = dst[i];
    if (d >= nlo && d < nhi) {
      int sh = (d & 1) << 4;
      unsigned old = atomicAdd(&cur[(d >> 1) - plo], 1u << sh);
      int local = (int)((old >> sh) & 0xFFFFu);
      csr_src[row_ptr[d] + local] = src[i];
    }
  }
}

// ---------------- prescale feats -> fp16 (+ fold in weight transpose) ----------------
#define WPTOT (F_IN * F_H1 + F_H1 * F_H2 + F_H2 * F_OUT)
__global__ void k_prewprep(const float* __restrict__ X, const float* __restrict__ ns,
                           __half* __restrict__ Y,
                           const float* __restrict__ W1, const float* __restrict__ W2,
                           const float* __restrict__ W3, __half* __restrict__ wt1,
                           __half* __restrict__ wt2, __half* __restrict__ wt3) {
  int i = blockIdx.x * 256 + threadIdx.x;
  if (i < NODES * 32) {   // prescale: 32 float4 per 128-col row
    int row = i >> 5;
    float s = ns[row];
    float4 v = reinterpret_cast<const float4*>(X)[i];
    __half2 h0 = __floats2half2_rn(v.x * s, v.y * s);
    __half2 h1 = __floats2half2_rn(v.z * s, v.w * s);
    union { struct { __half2 a, b; } h; uint2 u; } o;
    o.h.a = h0; o.h.b = h1;
    reinterpret_cast<uint2*>(Y)[i] = o.u;
  }
  if (i < WPTOT) {        // weight transpose -> fp16
    if (i < F_IN * F_H1) {
      int k = i >> 8, n = i & 255;
      wt1[(size_t)n * F_IN + k] = __float2half_rn(W1[i]);
    } else if (i < F_IN * F_H1 + F_H1 * F_H2) {
      int j = i - F_IN * F_H1;
      int k = j >> 8, n = j & 255;
      wt2[(size_t)n * F_H1 + k] = __float2half_rn(W2[j]);
    } else {
      int j = i - F_IN * F_H1 - F_H1 * F_H2;
      int k = j >> 6, n = j & 63;
      wt3[(size_t)n * F_H2 + k] = __float2half_rn(W3[j]);
    }
  }
}

// ---------------- fp16 gather helpers ----------------
struct u32x8s { uint4 a, b; };
template <int HPL> struct raw_t_sel;
template <> struct raw_t_sel<2> { using type = unsigned int; };
template <> struct raw_t_sel<4> { using type = uint2; };
template <> struct raw_t_sel<8> { using type = uint4; };
template <> struct raw_t_sel<16> { using type = u32x8s; };

template <int HPL>
__device__ __forceinline__ typename raw_t_sel<HPL>::type graw(const __half* p) {
  if constexpr (HPL == 16) {
    u32x8s r;
    r.a = *reinterpret_cast<const uint4*>(p);
    r.b = *reinterpret_cast<const uint4*>(p + 8);
    return r;
  } else {
    return *reinterpret_cast<const typename raw_t_sel<HPL>::type*>(p);
  }
}
__device__ __forceinline__ void acc_u32(float* acc, unsigned u) {
  union { unsigned u; __half2 h; } a; a.u = u;
  float2 f = __half22float2(a.h);
  acc[0] += f.x; acc[1] += f.y;
}
template <int HPL>
__device__ __forceinline__ void raw_acc(float* acc, typename raw_t_sel<HPL>::type r) {
  if constexpr (HPL == 16) {
    acc_u32(acc + 0, r.a.x);  acc_u32(acc + 2, r.a.y);
    acc_u32(acc + 4, r.a.z);  acc_u32(acc + 6, r.a.w);
    acc_u32(acc + 8, r.b.x);  acc_u32(acc + 10, r.b.y);
    acc_u32(acc + 12, r.b.z); acc_u32(acc + 14, r.b.w);
  } else if constexpr (HPL == 8) {
    acc_u32(acc + 0, r.x); acc_u32(acc + 2, r.y);
    acc_u32(acc + 4, r.z); acc_u32(acc + 6, r.w);
  } else if constexpr (HPL == 4) {
    acc_u32(acc + 0, r.x); acc_u32(acc + 2, r.y);
  } else {
    acc_u32(acc, r);
  }
}

// ---------------- SpMM (fp16 source): Y[v] = nd[v]*(X[v] + sum_{u->v} X[u]) (+bias)
// EPI edges per wave-iteration: lane = (sub-edge, feature-slot); butterfly
// shfl_xor combine at the end. OHALF: fp16 out, else f32.
template <int D, int EPI, bool BIAS, bool OHALF>
__global__ __launch_bounds__(256) void k_spmm_h(
    const __half* __restrict__ X, const int* __restrict__ row_ptr,
    const int* __restrict__ csr_src, const float* __restrict__ nd,
    const float* __restrict__ bias, void* __restrict__ Y, int n) {
  constexpr int LPN = 64 / EPI;    // lanes per edge-row
  constexpr int HPL = D / LPN;     // halves per lane
  static_assert(HPL >= 2 && HPL <= 16, "bad HPL");
  const int v = (blockIdx.x * blockDim.x + threadIdx.x) >> 6;
  const int lane = threadIdx.x & 63;
  if (v >= n) return;
  const int sub = lane / LPN;
  const int fl = lane % LPN;
  const int off = fl * HPL;
  const __half* __restrict__ Xo = X + off;

  float acc[HPL] = {};
  if (sub == 0) raw_acc<HPL>(acc, graw<HPL>(Xo + (size_t)v * D));   // self term

  const int beg = row_ptr[v];
  const int end = row_ptr[v + 1];
#pragma unroll 2
  for (int e = beg + sub; e < end; e += EPI) {
    int u = csr_src[e];
    raw_acc<HPL>(acc, graw<HPL>(Xo + (size_t)u * D));
  }

#pragma unroll
  for (int o = LPN; o < 64; o <<= 1)
#pragma unroll
    for (int i = 0; i < HPL; ++i) acc[i] += __shfl_xor(acc[i], o);

  if (sub != 0) return;
  const float sc = nd[v];
  float o[HPL];
#pragma unroll
  for (int i = 0; i < HPL; ++i) {
    o[i] = sc * acc[i];
    if (BIAS) o[i] += bias[off + i];
  }

  if constexpr (OHALF) {
    __half* yp = reinterpret_cast<__half*>(Y) + (size_t)v * D + off;
    if constexpr (HPL == 16) {
      union { struct { __half2 a, b, c, d; } h; uint4 u; } p0, p1;
      p0.h.a = __floats2half2_rn(o[0], o[1]);
      p0.h.b = __floats2half2_rn(o[2], o[3]);
      p0.h.c = __floats2half2_rn(o[4], o[5]);
      p0.h.d = __floats2half2_rn(o[6], o[7]);
      p1.h.a = __floats2half2_rn(o[8], o[9]);
      p1.h.b = __floats2half2_rn(o[10], o[11]);
      p1.h.c = __floats2half2_rn(o[12], o[13]);
      p1.h.d = __floats2half2_rn(o[14], o[15]);
      *reinterpret_cast<uint4*>(yp) = p0.u;
      *reinterpret_cast<uint4*>(yp + 8) = p1.u;
    } else if constexpr (HPL == 8) {
      union { struct { __half2 a, b, c, d; } h; uint4 u; } pk;
      pk.h.a = __floats2half2_rn(o[0], o[1]);
      pk.h.b = __floats2half2_rn(o[2], o[3]);
      pk.h.c = __floats2half2_rn(o[4], o[5]);
      pk.h.d = __floats2half2_rn(o[6], o[7]);
      *reinterpret_cast<uint4*>(yp) = pk.u;
    } else if constexpr (HPL == 4) {
      union { struct { __half2 a, b; } h; uint2 u; } pk;
      pk.h.a = __floats2half2_rn(o[0], o[1]);
      pk.h.b = __floats2half2_rn(o[2], o[3]);
      *reinterpret_cast<uint2*>(yp) = pk.u;
    } else {
      *reinterpret_cast<__half2*>(yp) = __floats2half2_rn(o[0], o[1]);
    }
  } else {
    float* yp = reinterpret_cast<float*>(Y) + (size_t)v * D + off;
    if constexpr (HPL == 8) {
      *reinterpret_cast<float4*>(yp) = make_float4(o[0], o[1], o[2], o[3]);
      *reinterpret_cast<float4*>(yp + 4) = make_float4(o[4], o[5], o[6], o[7]);
    } else if constexpr (HPL == 4) {
      *reinterpret_cast<float4*>(yp) = make_float4(o[0], o[1], o[2], o[3]);
    } else {
      *reinterpret_cast<float2*>(yp) = make_float2(o[0], o[1]);
    }
  }
}

// ---------------- pure-fp16 MFMA GEMM ----------------
template <int K, int NOUT, int BM, int WM, int WN, int MF, int NF,
          bool RELU, bool BIAS, bool NSOUT, bool OHALF>
__global__ __launch_bounds__(256) void k_gemm_h(
    const __half* __restrict__ A, const __half* __restrict__ Wt,
    const float* __restrict__ bias, const float* __restrict__ ns,
    void* __restrict__ C, int M) {
  constexpr int BN = WN * NF * 16;
  static_assert(BM == WM * MF * 16, "BM mismatch");
  static_assert(BN == NOUT, "BN must equal NOUT");
  constexpr int LDP = 40;  // 80B row stride -> bank stride 20 -> <=2-way (free), 16B aligned

  __shared__ __half As[BM][LDP];
  __shared__ __half Ws[BN][LDP];

  const int tid = threadIdx.x;
  const int bm = blockIdx.x * BM;
  const int lane = tid & 63;
  const int wave = tid >> 6;
  const int wmi = wave / WN;
  const int wni = wave % WN;
  const int rl = lane & 15;
  const int kg = lane >> 4;       // 0..3
  const int kb = kg * 8;

  f32x4 acc[MF][NF];
#pragma unroll
  for (int m = 0; m < MF; ++m)
#pragma unroll
    for (int n = 0; n < NF; ++n) acc[m][n] = (f32x4){0.f, 0.f, 0.f, 0.f};

  for (int kk = 0; kk < K; kk += 32) {
#pragma unroll
    for (int s0 = 0; s0 < BM * 4; s0 += 256) {
      int s = s0 + tid;
      int r = s >> 2, c8 = (s & 3) << 3;
      int grow = bm + r;
      ushort8v v = (ushort8v){0, 0, 0, 0, 0, 0, 0, 0};
      if (grow < M)
        v = *reinterpret_cast<const ushort8v*>(A + (size_t)grow * K + kk + c8);
      *reinterpret_cast<ushort8v*>(&As[r][c8]) = v;
    }
#pragma unroll
    for (int s0 = 0; s0 < BN * 4; s0 += 256) {
      int s = s0 + tid;
      int nn = s >> 2, k8 = (s & 3) << 3;
      *reinterpret_cast<ushort8v*>(&Ws[nn][k8]) =
          *reinterpret_cast<const ushort8v*>(Wt + (size_t)nn * K + kk + k8);
    }
    __syncthreads();

    f16x8 af[MF], bf[NF];
#pragma unroll
    for (int m = 0; m < MF; ++m) {
      const int r = wmi * MF * 16 + m * 16 + rl;
      af[m] = *reinterpret_cast<const f16x8*>(&As[r][kb]);
    }
#pragma unroll
    for (int n = 0; n < NF; ++n) {
      const int c = wni * NF * 16 + n * 16 + rl;
      bf[n] = *reinterpret_cast<const f16x8*>(&Ws[c][kb]);
    }
#pragma unroll
    for (int m = 0; m < MF; ++m)
#pragma unroll
      for (int n = 0; n < NF; ++n)
        acc[m][n] = __builtin_amdgcn_mfma_f32_16x16x32_f16(af[m], bf[n], acc[m][n], 0, 0, 0);
    __syncthreads();
  }

#pragma unroll
  for (int m = 0; m < MF; ++m) {
#pragma unroll
    for (int n = 0; n < NF; ++n) {
      const int col = wni * NF * 16 + n * 16 + rl;
      const float bb = BIAS ? bias[col] : 0.f;
      const int rowbase = bm + wmi * MF * 16 + m * 16 + kg * 4;
#pragma unroll
      for (int i = 0; i < 4; ++i) {
        int grow = rowbase + i;
        if (grow < M) {
          float val = acc[m][n][i] + bb;
          if (RELU) val = fmaxf(val, 0.f);
          if (NSOUT) val *= ns[grow];
          if constexpr (OHALF)
            reinterpret_cast<__half*>(C)[(size_t)grow * NOUT + col] = __float2half_rn(val);
          else
            reinterpret_cast<float*>(C)[(size_t)grow * NOUT + col] = val;
        }
      }
    }
  }
}

// ---------------- launch ----------------
extern "C" void kernel_launch(void* const* d_in, const int* in_sizes, int n_in,
                              void* d_out, int out_size, void* d_ws, size_t ws_size,
                              hipStream_t stream) {
  const float* feats = (const float*)d_in[0];
  const float* W1 = (const float*)d_in[1];
  const float* b1 = (const float*)d_in[2];
  const float* W2 = (const float*)d_in[3];
  const float* b2 = (const float*)d_in[4];
  const float* W3 = (const float*)d_in[5];
  const float* b3 = (const float*)d_in[6];
  const int* src = (const int*)d_in[7];
  const int* dst = (const int*)d_in[8];
  float* out = (float*)d_out;
  const int N = NODES;
  const int E = in_sizes[7];

  char* ws = (char*)d_ws;
  size_t off = 0;
  auto alloc = [&](size_t bytes) -> void* {
    void* p = ws + off;
    off += (bytes + 255) & ~(size_t)255;
    return p;
  };
  __half* w0h = (__half*)alloc((size_t)N * 256 * sizeof(__half));  // layer2 spmm out
  __half* w1r = (__half*)alloc((size_t)N * 256 * sizeof(__half));  // spmm1 out / gemm2 out
  __half* w2r = (__half*)alloc((size_t)N * 256 * sizeof(__half));  // prescaled feats / gemm1 out / gemm3 out
  float* ns = (float*)alloc((size_t)N * sizeof(float));
  float* nd = (float*)alloc((size_t)N * sizeof(float));
  int* row_ptr = (int*)alloc((size_t)(N + 1) * sizeof(int));
  int* csr_src = (int*)alloc((size_t)E * sizeof(int));
  int* psum = (int*)alloc((size_t)META_B * sizeof(int));
  unsigned* p_out = (unsigned*)alloc((size_t)SLICES * NPACK * sizeof(unsigned));
  unsigned* p_in = (unsigned*)alloc((size_t)SLICES * NPACK * sizeof(unsigned));
  unsigned* base_in = (unsigned*)alloc((size_t)SLICES * NPACK * sizeof(unsigned));
  __half* wt1 = (__half*)alloc((size_t)F_IN * F_H1 * sizeof(__half));
  __half* wt2 = (__half*)alloc((size_t)F_H1 * F_H2 * sizeof(__half));
  __half* wt3 = (__half*)alloc((size_t)F_H2 * F_OUT * sizeof(__half));
  (void)ws_size; (void)n_in; (void)out_size;

  // ---- 1. histogram (no global atomics) ----
  hipLaunchKernelGGL(k_hist2, dim3(SLICES * 4), dim3(512), 0, stream,
                     src, dst, p_out, p_in, E);

  // ---- 2. degnorm + full scan (cooperative, grid-wide sync) ----
  {
    void* args[] = {(void*)&p_out, (void*)&p_in, (void*)&base_in, (void*)&ns,
                    (void*)&nd, (void*)&psum, (void*)&row_ptr};
    hipLaunchCooperativeKernel((void*)k_csrmeta, dim3(META_B), dim3(256), args, 0, stream);
  }

  // ---- 3. counting-sort scatter ----
  hipLaunchKernelGGL(k_scatter4, dim3(SLICES * 4), dim3(512), 0, stream,
                     src, dst, row_ptr, base_in, csr_src, E);

  // ---- 4. prescale feats -> fp16 (+ weight transpose folded in) ----
  hipLaunchKernelGGL(k_prewprep, dim3((N * 32 + 255) / 256), dim3(256), 0, stream,
                     feats, ns, w2r, W1, W2, W3, wt1, wt2, wt3);

  auto grid_w = [](int waves) { return dim3((waves + 3) / 4); };  // 4 waves/block

  // ---- 5/6. layer 1: SpMM(d=128, EPI=8) -> fp16; GEMM 128->256 (+b1, relu, *ns) -> fp16
  hipLaunchKernelGGL((k_spmm_h<128, 8, false, true>), grid_w(N), dim3(256), 0, stream,
                     w2r, row_ptr, csr_src, nd, nullptr, w1r, N);
  hipLaunchKernelGGL((k_gemm_h<128, 256, 64, 1, 4, 4, 4, true, true, true, true>),
                     dim3((N + 63) / 64), dim3(256), 0, stream,
                     w1r, wt1, b1, ns, w2r, N);

  // ---- 7/8. layer 2: SpMM(d=256, EPI=4) -> fp16; GEMM 256->256 (+b2, relu, *ns) -> fp16
  hipLaunchKernelGGL((k_spmm_h<256, 4, false, true>), grid_w(N), dim3(256), 0, stream,
                     w2r, row_ptr, csr_src, nd, nullptr, w0h, N);
  hipLaunchKernelGGL((k_gemm_h<256, 256, 64, 1, 4, 4, 4, true, true, true, true>),
                     dim3((N + 63) / 64), dim3(256), 0, stream,
                     w0h, wt2, b2, ns, w1r, N);

  // ---- 9/10. layer 3: GEMM 256->64 (no act) -> fp16; SpMM(d=64, EPI=8) +b3 -> out f32
  hipLaunchKernelGGL((k_gemm_h<256, 64, 128, 4, 1, 2, 4, false, false, false, true>),
                     dim3((N + 127) / 128), dim3(256), 0, stream,
                     w1r, wt3, nullptr, nullptr, w2r, N);
  hipLaunchKernelGGL((k_spmm_h<64, 8, true, false>), dim3((N + 3) / 4), dim3(256), 0, stream,
                     w2r, row_ptr, csr_src, nd, b3, out, N);
}

// Round 13
// 273.207 us; speedup vs baseline: 1.2892x; 1.0334x over previous
//
#include <hip/hip_runtime.h>
#include <hip/hip_fp16.h>
#include <stdint.h>

// ---------------- problem constants ----------------
#define NODES 50000
#define F_IN 128
#define F_H1 256
#define F_H2 256
#define F_OUT 64
#define SLICES 64            // edge slices for hist/scatter
#define NPACK (NODES / 2)    // packed ushort-pair bins (25000)
#define QPACK (NPACK / 4)    // bins per node-quarter (6250, 25 KB LDS per array)

using f32x4    = __attribute__((ext_vector_type(4))) float;
using f16x8    = __attribute__((ext_vector_type(8))) _Float16;   // 8 fp16 in 4 VGPRs
using ushort8v = __attribute__((ext_vector_type(8))) unsigned short;

// ---------------- atomic-free degree/CSR machinery ----------------
__global__ __launch_bounds__(512) void k_hist2(
    const int* __restrict__ src, const int* __restrict__ dst,
    unsigned* __restrict__ p_out, unsigned* __restrict__ p_in, int e) {
  __shared__ unsigned bo[QPACK];
  __shared__ unsigned bi[QPACK];
  const int s = blockIdx.x >> 2;
  const int r = blockIdx.x & 3;
  const int nlo = r * (NODES / 4);
  const int nhi = nlo + NODES / 4;
  const int plo = r * QPACK;
  const int per = (e + SLICES - 1) / SLICES;
  const int beg = s * per;
  const int end = min(e, beg + per);

  for (int j = threadIdx.x; j < QPACK; j += 512) { bo[j] = 0; bi[j] = 0; }
  __syncthreads();
  for (int i = beg + (int)threadIdx.x; i < end; i += 512) {
    int a = src[i];
    if (a >= nlo && a < nhi)
      atomicAdd(&bo[(a >> 1) - plo], 1u << ((a & 1) << 4));
    int d = dst[i];
    if (d >= nlo && d < nhi)
      atomicAdd(&bi[(d >> 1) - plo], 1u << ((d & 1) << 4));
  }
  __syncthreads();
  for (int j = threadIdx.x; j < QPACK; j += 512) {
    p_out[(size_t)s * NPACK + plo + j] = bo[j];
    p_in[(size_t)s * NPACK + plo + j] = bi[j];
  }
}

__global__ __launch_bounds__(256) void k_degnorm(
    const unsigned* __restrict__ p_out, const unsigned* __restrict__ p_in,
    unsigned* __restrict__ base_in, int* __restrict__ deg_in,
    float* __restrict__ ns, float* __restrict__ nd) {
  int p = blockIdx.x * 256 + threadIdx.x;
  if (p >= NPACK) return;
  unsigned so = 0, si = 0;
#pragma unroll 4
  for (int s = 0; s < SLICES; ++s) {
    so += p_out[(size_t)s * NPACK + p];
    unsigned vi = p_in[(size_t)s * NPACK + p];
    base_in[(size_t)s * NPACK + p] = si;   // exclusive prefix across slices
    si += vi;
  }
  int o0 = (int)(so & 0xFFFFu) + 1, o1 = (int)(so >> 16) + 1;   // +1 self-loop
  int i0 = (int)(si & 0xFFFFu) + 1, i1 = (int)(si >> 16) + 1;
  int n0 = p * 2, n1 = n0 + 1;
  deg_in[n0] = i0; deg_in[n1] = i1;
  ns[n0] = rsqrtf((float)o0); ns[n1] = rsqrtf((float)o1);
  nd[n0] = rsqrtf((float)i0); nd[n1] = rsqrtf((float)i1);
}

// ---------------- parallel 3-phase exclusive scan over (deg_in - 1) ----------------
__global__ __launch_bounds__(256) void k_scan1(const int* __restrict__ deg_in,
                                               int* __restrict__ psum, int n) {
  int i = blockIdx.x * 256 + threadIdx.x;
  int v = (i < n) ? deg_in[i] - 1 : 0;
#pragma unroll
  for (int o = 1; o < 64; o <<= 1) v += __shfl_xor(v, o);
  __shared__ int ws[4];
  if ((threadIdx.x & 63) == 0) ws[threadIdx.x >> 6] = v;
  __syncthreads();
  if (threadIdx.x == 0) psum[blockIdx.x] = ws[0] + ws[1] + ws[2] + ws[3];
}

__global__ __launch_bounds__(256) void k_scan2(int* __restrict__ psum, int nb) {
  __shared__ int s[256];
  int t = threadIdx.x;
  int v = (t < nb) ? psum[t] : 0;
  s[t] = v;
  __syncthreads();
  for (int o = 1; o < 256; o <<= 1) {
    int u = (t >= o) ? s[t - o] : 0;
    __syncthreads();
    s[t] += u;
    __syncthreads();
  }
  if (t < nb) psum[t] = s[t] - v;   // exclusive
}

__global__ __launch_bounds__(256) void k_scan3(const int* __restrict__ deg_in,
                                               const int* __restrict__ psum,
                                               int* __restrict__ row_ptr, int n) {
  int i = blockIdx.x * 256 + threadIdx.x;
  int lane = threadIdx.x & 63;
  int w = threadIdx.x >> 6;
  int v = (i < n) ? deg_in[i] - 1 : 0;
  int x = v;
#pragma unroll
  for (int o = 1; o < 64; o <<= 1) {
    int u = __shfl_up(x, o);
    if (lane >= o) x += u;
  }
  __shared__ int wsum[4];
  if (lane == 63) wsum[w] = x;
  __syncthreads();
  int woff = 0;
#pragma unroll
  for (int j = 0; j < 4; ++j)
    if (j < w) woff += wsum[j];
  int excl = x - v + woff + psum[blockIdx.x];
  if (i < n) row_ptr[i] = excl;
  if (i == n - 1) row_ptr[n] = excl + v;
}

__global__ __launch_bounds__(512) void k_scatter4(
    const int* __restrict__ src, const int* __restrict__ dst,
    const int* __restrict__ row_ptr, const unsigned* __restrict__ base_in,
    int* __restrict__ csr_src, int e) {
  __shared__ unsigned cur[QPACK];
  const int s = blockIdx.x >> 2;
  const int r = blockIdx.x & 3;
  const int nlo = r * (NODES / 4);
  const int nhi = nlo + NODES / 4;
  const int plo = r * QPACK;
  const int per = (e + SLICES - 1) / SLICES;
  const int beg = s * per;
  const int end = min(e, beg + per);
  for (int j = threadIdx.x; j < QPACK; j += 512)
    cur[j] = base_in[(size_t)s * NPACK + plo + j];
  __syncthreads();
  for (int i = beg + (int)threadIdx.x; i < end; i += 512) {
    int d = dst[i];
    if (d >= nlo && d < nhi) {
      int sh = (d & 1) << 4;
      unsigned old = atomicAdd(&cur[(d >> 1) - plo], 1u << sh);
      int local = (int)((old >> sh) & 0xFFFFu);
      csr_src[row_ptr[d] + local] = src[i];
    }
  }
}

// ---------------- prescale feats -> fp16 (+ weight transpose folded in) ----------------
#define WPTOT (F_IN * F_H1 + F_H1 * F_H2 + F_H2 * F_OUT)
__global__ void k_prewprep(const float* __restrict__ X, const float* __restrict__ ns,
                           __half* __restrict__ Y,
                           const float* __restrict__ W1, const float* __restrict__ W2,
                           const float* __restrict__ W3, __half* __restrict__ wt1,
                           __half* __restrict__ wt2, __half* __restrict__ wt3) {
  int i = blockIdx.x * 256 + threadIdx.x;
  if (i < NODES * 32) {   // prescale: 32 float4 per 128-col row
    int row = i >> 5;
    float s = ns[row];
    float4 v = reinterpret_cast<const float4*>(X)[i];
    __half2 h0 = __floats2half2_rn(v.x * s, v.y * s);
    __half2 h1 = __floats2half2_rn(v.z * s, v.w * s);
    union { struct { __half2 a, b; } h; uint2 u; } o;
    o.h.a = h0; o.h.b = h1;
    reinterpret_cast<uint2*>(Y)[i] = o.u;
  }
  if (i < WPTOT) {        // weight transpose -> fp16
    if (i < F_IN * F_H1) {
      int k = i >> 8, n = i & 255;
      wt1[(size_t)n * F_IN + k] = __float2half_rn(W1[i]);
    } else if (i < F_IN * F_H1 + F_H1 * F_H2) {
      int j = i - F_IN * F_H1;
      int k = j >> 8, n = j & 255;
      wt2[(size_t)n * F_H1 + k] = __float2half_rn(W2[j]);
    } else {
      int j = i - F_IN * F_H1 - F_H1 * F_H2;
      int k = j >> 6, n = j & 63;
      wt3[(size_t)n * F_H2 + k] = __float2half_rn(W3[j]);
    }
  }
}

// ---------------- fp16 gather helpers ----------------
struct u32x8s { uint4 a, b; };
template <int HPL> struct raw_t_sel;
template <> struct raw_t_sel<2> { using type = unsigned int; };
template <> struct raw_t_sel<4> { using type = uint2; };
template <> struct raw_t_sel<8> { using type = uint4; };
template <> struct raw_t_sel<16> { using type = u32x8s; };

template <int HPL>
__device__ __forceinline__ typename raw_t_sel<HPL>::type graw(const __half* p) {
  if constexpr (HPL == 16) {
    u32x8s r;
    r.a = *reinterpret_cast<const uint4*>(p);
    r.b = *reinterpret_cast<const uint4*>(p + 8);
    return r;
  } else {
    return *reinterpret_cast<const typename raw_t_sel<HPL>::type*>(p);
  }
}
__device__ __forceinline__ void acc_u32(float* acc, unsigned u) {
  union { unsigned u; __half2 h; } a; a.u = u;
  float2 f = __half22float2(a.h);
  acc[0] += f.x; acc[1] += f.y;
}
template <int HPL>
__device__ __forceinline__ void raw_acc(float* acc, typename raw_t_sel<HPL>::type r) {
  if constexpr (HPL == 16) {
    acc_u32(acc + 0, r.a.x);  acc_u32(acc + 2, r.a.y);
    acc_u32(acc + 4, r.a.z);  acc_u32(acc + 6, r.a.w);
    acc_u32(acc + 8, r.b.x);  acc_u32(acc + 10, r.b.y);
    acc_u32(acc + 12, r.b.z); acc_u32(acc + 14, r.b.w);
  } else if constexpr (HPL == 8) {
    acc_u32(acc + 0, r.x); acc_u32(acc + 2, r.y);
    acc_u32(acc + 4, r.z); acc_u32(acc + 6, r.w);
  } else if constexpr (HPL == 4) {
    acc_u32(acc + 0, r.x); acc_u32(acc + 2, r.y);
  } else {
    acc_u32(acc, r);
  }
}

// ---------------- SpMM (fp16 source): Y[v] = nd[v]*(X[v] + sum_{u->v} X[u]) (+bias)
// EPI edges per wave-iteration: lane = (sub-edge, feature-slot); butterfly
// shfl_xor combine at the end. OHALF: fp16 out, else f32.
template <int D, int EPI, bool BIAS, bool OHALF>
__global__ __launch_bounds__(256) void k_spmm_h(
    const __half* __restrict__ X, const int* __restrict__ row_ptr,
    const int* __restrict__ csr_src, const float* __restrict__ nd,
    const float* __restrict__ bias, void* __restrict__ Y, int n) {
  constexpr int LPN = 64 / EPI;    // lanes per edge-row
  constexpr int HPL = D / LPN;     // halves per lane
  static_assert(HPL >= 2 && HPL <= 16, "bad HPL");
  const int v = (blockIdx.x * blockDim.x + threadIdx.x) >> 6;
  const int lane = threadIdx.x & 63;
  if (v >= n) return;
  const int sub = lane / LPN;
  const int fl = lane % LPN;
  const int off = fl * HPL;
  const __half* __restrict__ Xo = X + off;

  float acc[HPL] = {};
  if (sub == 0) raw_acc<HPL>(acc, graw<HPL>(Xo + (size_t)v * D));   // self term

  const int beg = row_ptr[v];
  const int end = row_ptr[v + 1];
#pragma unroll 2
  for (int e = beg + sub; e < end; e += EPI) {
    int u = csr_src[e];
    raw_acc<HPL>(acc, graw<HPL>(Xo + (size_t)u * D));
  }

#pragma unroll
  for (int o = LPN; o < 64; o <<= 1)
#pragma unroll
    for (int i = 0; i < HPL; ++i) acc[i] += __shfl_xor(acc[i], o);

  if (sub != 0) return;
  const float sc = nd[v];
  float o[HPL];
#pragma unroll
  for (int i = 0; i < HPL; ++i) {
    o[i] = sc * acc[i];
    if (BIAS) o[i] += bias[off + i];
  }

  if constexpr (OHALF) {
    __half* yp = reinterpret_cast<__half*>(Y) + (size_t)v * D + off;
    if constexpr (HPL == 16) {
      union { struct { __half2 a, b, c, d; } h; uint4 u; } p0, p1;
      p0.h.a = __floats2half2_rn(o[0], o[1]);
      p0.h.b = __floats2half2_rn(o[2], o[3]);
      p0.h.c = __floats2half2_rn(o[4], o[5]);
      p0.h.d = __floats2half2_rn(o[6], o[7]);
      p1.h.a = __floats2half2_rn(o[8], o[9]);
      p1.h.b = __floats2half2_rn(o[10], o[11]);
      p1.h.c = __floats2half2_rn(o[12], o[13]);
      p1.h.d = __floats2half2_rn(o[14], o[15]);
      *reinterpret_cast<uint4*>(yp) = p0.u;
      *reinterpret_cast<uint4*>(yp + 8) = p1.u;
    } else if constexpr (HPL == 8) {
      union { struct { __half2 a, b, c, d; } h; uint4 u; } pk;
      pk.h.a = __floats2half2_rn(o[0], o[1]);
      pk.h.b = __floats2half2_rn(o[2], o[3]);
      pk.h.c = __floats2half2_rn(o[4], o[5]);
      pk.h.d = __floats2half2_rn(o[6], o[7]);
      *reinterpret_cast<uint4*>(yp) = pk.u;
    } else if constexpr (HPL == 4) {
      union { struct { __half2 a, b; } h; uint2 u; } pk;
      pk.h.a = __floats2half2_rn(o[0], o[1]);
      pk.h.b = __floats2half2_rn(o[2], o[3]);
      *reinterpret_cast<uint2*>(yp) = pk.u;
    } else {
      *reinterpret_cast<__half2*>(yp) = __floats2half2_rn(o[0], o[1]);
    }
  } else {
    float* yp = reinterpret_cast<float*>(Y) + (size_t)v * D + off;
    if constexpr (HPL == 8) {
      *reinterpret_cast<float4*>(yp) = make_float4(o[0], o[1], o[2], o[3]);
      *reinterpret_cast<float4*>(yp + 4) = make_float4(o[4], o[5], o[6], o[7]);
    } else if constexpr (HPL == 4) {
      *reinterpret_cast<float4*>(yp) = make_float4(o[0], o[1], o[2], o[3]);
    } else {
      *reinterpret_cast<float2*>(yp) = make_float2(o[0], o[1]);
    }
  }
}

// ---------------- pure-fp16 MFMA GEMM ----------------
template <int K, int NOUT, int BM, int WM, int WN, int MF, int NF,
          bool RELU, bool BIAS, bool NSOUT, bool OHALF>
__global__ __launch_bounds__(256) void k_gemm_h(
    const __half* __restrict__ A, const __half* __restrict__ Wt,
    const float* __restrict__ bias, const float* __restrict__ ns,
    void* __restrict__ C, int M) {
  constexpr int BN = WN * NF * 16;
  static_assert(BM == WM * MF * 16, "BM mismatch");
  static_assert(BN == NOUT, "BN must equal NOUT");
  static_assert((BM * 4) % 256 == 0, "staging loop divisibility");
  constexpr int LDP = 40;  // 80B row stride -> bank stride 20 -> <=2-way (free), 16B aligned

  __shared__ __half As[BM][LDP];
  __shared__ __half Ws[BN][LDP];

  const int tid = threadIdx.x;
  const int bm = blockIdx.x * BM;
  const int lane = tid & 63;
  const int wave = tid >> 6;
  const int wmi = wave / WN;
  const int wni = wave % WN;
  const int rl = lane & 15;
  const int kg = lane >> 4;       // 0..3
  const int kb = kg * 8;

  f32x4 acc[MF][NF];
#pragma unroll
  for (int m = 0; m < MF; ++m)
#pragma unroll
    for (int n = 0; n < NF; ++n) acc[m][n] = (f32x4){0.f, 0.f, 0.f, 0.f};

  for (int kk = 0; kk < K; kk += 32) {
#pragma unroll
    for (int s0 = 0; s0 < BM * 4; s0 += 256) {
      int s = s0 + tid;
      int r = s >> 2, c8 = (s & 3) << 3;
      int grow = bm + r;
      ushort8v v = (ushort8v){0, 0, 0, 0, 0, 0, 0, 0};
      if (grow < M)
        v = *reinterpret_cast<const ushort8v*>(A + (size_t)grow * K + kk + c8);
      *reinterpret_cast<ushort8v*>(&As[r][c8]) = v;
    }
#pragma unroll
    for (int s0 = 0; s0 < BN * 4; s0 += 256) {
      int s = s0 + tid;
      int nn = s >> 2, k8 = (s & 3) << 3;
      *reinterpret_cast<ushort8v*>(&Ws[nn][k8]) =
          *reinterpret_cast<const ushort8v*>(Wt + (size_t)nn * K + kk + k8);
    }
    __syncthreads();

    f16x8 af[MF], bf[NF];
#pragma unroll
    for (int m = 0; m < MF; ++m) {
      const int r = wmi * MF * 16 + m * 16 + rl;
      af[m] = *reinterpret_cast<const f16x8*>(&As[r][kb]);
    }
#pragma unroll
    for (int n = 0; n < NF; ++n) {
      const int c = wni * NF * 16 + n * 16 + rl;
      bf[n] = *reinterpret_cast<const f16x8*>(&Ws[c][kb]);
    }
#pragma unroll
    for (int m = 0; m < MF; ++m)
#pragma unroll
      for (int n = 0; n < NF; ++n)
        acc[m][n] = __builtin_amdgcn_mfma_f32_16x16x32_f16(af[m], bf[n], acc[m][n], 0, 0, 0);
    __syncthreads();
  }

#pragma unroll
  for (int m = 0; m < MF; ++m) {
#pragma unroll
    for (int n = 0; n < NF; ++n) {
      const int col = wni * NF * 16 + n * 16 + rl;
      const float bb = BIAS ? bias[col] : 0.f;
      const int rowbase = bm + wmi * MF * 16 + m * 16 + kg * 4;
#pragma unroll
      for (int i = 0; i < 4; ++i) {
        int grow = rowbase + i;
        if (grow < M) {
          float val = acc[m][n][i] + bb;
          if (RELU) val = fmaxf(val, 0.f);
          if (NSOUT) val *= ns[grow];
          if constexpr (OHALF)
            reinterpret_cast<__half*>(C)[(size_t)grow * NOUT + col] = __float2half_rn(val);
          else
            reinterpret_cast<float*>(C)[(size_t)grow * NOUT + col] = val;
        }
      }
    }
  }
}

// ---------------- launch ----------------
extern "C" void kernel_launch(void* const* d_in, const int* in_sizes, int n_in,
                              void* d_out, int out_size, void* d_ws, size_t ws_size,
                              hipStream_t stream) {
  const float* feats = (const float*)d_in[0];
  const float* W1 = (const float*)d_in[1];
  const float* b1 = (const float*)d_in[2];
  const float* W2 = (const float*)d_in[3];
  const float* b2 = (const float*)d_in[4];
  const float* W3 = (const float*)d_in[5];
  const float* b3 = (const float*)d_in[6];
  const int* src = (const int*)d_in[7];
  const int* dst = (const int*)d_in[8];
  float* out = (float*)d_out;
  const int N = NODES;
  const int E = in_sizes[7];
  const int NB = (N + 255) / 256;          // scan blocks (196 <= 256)

  char* ws = (char*)d_ws;
  size_t off = 0;
  auto alloc = [&](size_t bytes) -> void* {
    void* p = ws + off;
    off += (bytes + 255) & ~(size_t)255;
    return p;
  };
  __half* w0h = (__half*)alloc((size_t)N * 256 * sizeof(__half));  // spmm2 out
  __half* w1r = (__half*)alloc((size_t)N * 256 * sizeof(__half));  // spmm1 out / gemm2 out
  __half* w2r = (__half*)alloc((size_t)N * 256 * sizeof(__half));  // prescaled feats / gemm1 out / gemm3 out
  int* deg_in = (int*)alloc((size_t)N * sizeof(int));
  float* ns = (float*)alloc((size_t)N * sizeof(float));
  float* nd = (float*)alloc((size_t)N * sizeof(float));
  int* row_ptr = (int*)alloc((size_t)(N + 1) * sizeof(int));
  int* csr_src = (int*)alloc((size_t)E * sizeof(int));
  int* psum = (int*)alloc((size_t)NB * sizeof(int));
  unsigned* p_out = (unsigned*)alloc((size_t)SLICES * NPACK * sizeof(unsigned));
  unsigned* p_in = (unsigned*)alloc((size_t)SLICES * NPACK * sizeof(unsigned));
  unsigned* base_in = (unsigned*)alloc((size_t)SLICES * NPACK * sizeof(unsigned));
  __half* wt1 = (__half*)alloc((size_t)F_IN * F_H1 * sizeof(__half));
  __half* wt2 = (__half*)alloc((size_t)F_H1 * F_H2 * sizeof(__half));
  __half* wt3 = (__half*)alloc((size_t)F_H2 * F_OUT * sizeof(__half));
  (void)ws_size; (void)n_in; (void)out_size;

  // ---- graph preprocessing (no global atomics; round-10 proven chain) ----
  hipLaunchKernelGGL(k_hist2, dim3(SLICES * 4), dim3(512), 0, stream,
                     src, dst, p_out, p_in, E);
  hipLaunchKernelGGL(k_degnorm, dim3((NPACK + 255) / 256), dim3(256), 0, stream,
                     p_out, p_in, base_in, deg_in, ns, nd);
  hipLaunchKernelGGL(k_scan1, dim3(NB), dim3(256), 0, stream, deg_in, psum, N);
  hipLaunchKernelGGL(k_scan2, dim3(1), dim3(256), 0, stream, psum, NB);
  hipLaunchKernelGGL(k_scan3, dim3(NB), dim3(256), 0, stream, deg_in, psum, row_ptr, N);
  hipLaunchKernelGGL(k_scatter4, dim3(SLICES * 4), dim3(512), 0, stream,
                     src, dst, row_ptr, base_in, csr_src, E);

  // ---- prescale feats -> fp16 (+ weight transpose folded in) ----
  hipLaunchKernelGGL(k_prewprep, dim3((N * 32 + 255) / 256), dim3(256), 0, stream,
                     feats, ns, w2r, W1, W2, W3, wt1, wt2, wt3);

  auto grid_w = [](int waves) { return dim3((waves + 3) / 4); };  // 4 waves/block

  // ---- layer 1: SpMM(d=128, EPI=8) -> fp16; GEMM 128->256 (BM=128, +b1, relu, *ns) -> fp16
  hipLaunchKernelGGL((k_spmm_h<128, 8, false, true>), grid_w(N), dim3(256), 0, stream,
                     w2r, row_ptr, csr_src, nd, nullptr, w1r, N);
  hipLaunchKernelGGL((k_gemm_h<128, 256, 128, 1, 4, 8, 4, true, true, true, true>),
                     dim3((N + 127) / 128), dim3(256), 0, stream,
                     w1r, wt1, b1, ns, w2r, N);

  // ---- layer 2: SpMM(d=256, EPI=4) -> fp16; GEMM 256->256 (BM=128, +b2, relu, *ns) -> fp16
  hipLaunchKernelGGL((k_spmm_h<256, 4, false, true>), grid_w(N), dim3(256), 0, stream,
                     w2r, row_ptr, csr_src, nd, nullptr, w0h, N);
  hipLaunchKernelGGL((k_gemm_h<256, 256, 128, 1, 4, 8, 4, true, true, true, true>),
                     dim3((N + 127) / 128), dim3(256), 0, stream,
                     w0h, wt2, b2, ns, w1r, N);

  // ---- layer 3: GEMM 256->64 (no act) -> fp16; SpMM(d=64, EPI=8) +b3 -> out f32
  hipLaunchKernelGGL((k_gemm_h<256, 64, 128, 4, 1, 2, 4, false, false, false, true>),
                     dim3((N + 127) / 128), dim3(256), 0, stream,
                     w1r, wt3, nullptr, nullptr, w2r, N);
  hipLaunchKernelGGL((k_spmm_h<64, 8, true, false>), dim3((N + 3) / 4), dim3(256), 0, stream,
                     w2r, row_ptr, csr_src, nd, b3, out, N);
}

// Round 14
// 253.359 us; speedup vs baseline: 1.3902x; 1.0783x over previous
//
#include <hip/hip_runtime.h>
#include <hip/hip_fp16.h>
#include <stdint.h>

// ---------------- problem constants ----------------
#define NODES 50000
#define F_IN 128
#define F_H1 256
#define F_H2 256
#define F_OUT 64
#define SLICES 64            // edge slices for hist/scatter
#define NPACK (NODES / 2)    // packed ushort-pair bins (25000)
#define QPACK (NPACK / 4)    // bins per node-quarter (6250, 25 KB LDS per array)

using f32x4    = __attribute__((ext_vector_type(4))) float;
using f16x8    = __attribute__((ext_vector_type(8))) _Float16;   // 8 fp16 in 4 VGPRs
using ushort8v = __attribute__((ext_vector_type(8))) unsigned short;

// ---------------- atomic-free degree/CSR machinery ----------------
__global__ __launch_bounds__(512) void k_hist2(
    const int* __restrict__ src, const int* __restrict__ dst,
    unsigned* __restrict__ p_out, unsigned* __restrict__ p_in, int e) {
  __shared__ unsigned bo[QPACK];
  __shared__ unsigned bi[QPACK];
  const int s = blockIdx.x >> 2;
  const int r = blockIdx.x & 3;
  const int nlo = r * (NODES / 4);
  const int nhi = nlo + NODES / 4;
  const int plo = r * QPACK;
  const int per = (e + SLICES - 1) / SLICES;
  const int beg = s * per;
  const int end = min(e, beg + per);

  for (int j = threadIdx.x; j < QPACK; j += 512) { bo[j] = 0; bi[j] = 0; }
  __syncthreads();
  for (int i = beg + (int)threadIdx.x; i < end; i += 512) {
    int a = src[i];
    if (a >= nlo && a < nhi)
      atomicAdd(&bo[(a >> 1) - plo], 1u << ((a & 1) << 4));
    int d = dst[i];
    if (d >= nlo && d < nhi)
      atomicAdd(&bi[(d >> 1) - plo], 1u << ((d & 1) << 4));
  }
  __syncthreads();
  for (int j = threadIdx.x; j < QPACK; j += 512) {
    p_out[(size_t)s * NPACK + plo + j] = bo[j];
    p_in[(size_t)s * NPACK + plo + j] = bi[j];
  }
}

__global__ __launch_bounds__(256) void k_degnorm(
    const unsigned* __restrict__ p_out, const unsigned* __restrict__ p_in,
    unsigned* __restrict__ base_in, int* __restrict__ deg_in,
    float* __restrict__ ns, float* __restrict__ nd) {
  int p = blockIdx.x * 256 + threadIdx.x;
  if (p >= NPACK) return;
  unsigned so = 0, si = 0;
#pragma unroll 4
  for (int s = 0; s < SLICES; ++s) {
    so += p_out[(size_t)s * NPACK + p];
    unsigned vi = p_in[(size_t)s * NPACK + p];
    base_in[(size_t)s * NPACK + p] = si;   // exclusive prefix across slices
    si += vi;
  }
  int o0 = (int)(so & 0xFFFFu) + 1, o1 = (int)(so >> 16) + 1;   // +1 self-loop
  int i0 = (int)(si & 0xFFFFu) + 1, i1 = (int)(si >> 16) + 1;
  int n0 = p * 2, n1 = n0 + 1;
  deg_in[n0] = i0; deg_in[n1] = i1;
  ns[n0] = rsqrtf((float)o0); ns[n1] = rsqrtf((float)o1);
  nd[n0] = rsqrtf((float)i0); nd[n1] = rsqrtf((float)i1);
}

// ---------------- parallel 3-phase exclusive scan over (deg_in - 1) ----------------
__global__ __launch_bounds__(256) void k_scan1(const int* __restrict__ deg_in,
                                               int* __restrict__ psum, int n) {
  int i = blockIdx.x * 256 + threadIdx.x;
  int v = (i < n) ? deg_in[i] - 1 : 0;
#pragma unroll
  for (int o = 1; o < 64; o <<= 1) v += __shfl_xor(v, o);
  __shared__ int ws[4];
  if ((threadIdx.x & 63) == 0) ws[threadIdx.x >> 6] = v;
  __syncthreads();
  if (threadIdx.x == 0) psum[blockIdx.x] = ws[0] + ws[1] + ws[2] + ws[3];
}

__global__ __launch_bounds__(256) void k_scan2(int* __restrict__ psum, int nb) {
  __shared__ int s[256];
  int t = threadIdx.x;
  int v = (t < nb) ? psum[t] : 0;
  s[t] = v;
  __syncthreads();
  for (int o = 1; o < 256; o <<= 1) {
    int u = (t >= o) ? s[t - o] : 0;
    __syncthreads();
    s[t] += u;
    __syncthreads();
  }
  if (t < nb) psum[t] = s[t] - v;   // exclusive
}

__global__ __launch_bounds__(256) void k_scan3(const int* __restrict__ deg_in,
                                               const int* __restrict__ psum,
                                               int* __restrict__ row_ptr, int n) {
  int i = blockIdx.x * 256 + threadIdx.x;
  int lane = threadIdx.x & 63;
  int w = threadIdx.x >> 6;
  int v = (i < n) ? deg_in[i] - 1 : 0;
  int x = v;
#pragma unroll
  for (int o = 1; o < 64; o <<= 1) {
    int u = __shfl_up(x, o);
    if (lane >= o) x += u;
  }
  __shared__ int wsum[4];
  if (lane == 63) wsum[w] = x;
  __syncthreads();
  int woff = 0;
#pragma unroll
  for (int j = 0; j < 4; ++j)
    if (j < w) woff += wsum[j];
  int excl = x - v + woff + psum[blockIdx.x];
  if (i < n) row_ptr[i] = excl;
  if (i == n - 1) row_ptr[n] = excl + v;
}

__global__ __launch_bounds__(512) void k_scatter4(
    const int* __restrict__ src, const int* __restrict__ dst,
    const int* __restrict__ row_ptr, const unsigned* __restrict__ base_in,
    int* __restrict__ csr_src, int e) {
  __shared__ unsigned cur[QPACK];
  const int s = blockIdx.x >> 2;
  const int r = blockIdx.x & 3;
  const int nlo = r * (NODES / 4);
  const int nhi = nlo + NODES / 4;
  const int plo = r * QPACK;
  const int per = (e + SLICES - 1) / SLICES;
  const int beg = s * per;
  const int end = min(e, beg + per);
  for (int j = threadIdx.x; j < QPACK; j += 512)
    cur[j] = base_in[(size_t)s * NPACK + plo + j];
  __syncthreads();
  for (int i = beg + (int)threadIdx.x; i < end; i += 512) {
    int d = dst[i];
    if (d >= nlo && d < nhi) {
      int sh = (d & 1) << 4;
      unsigned old = atomicAdd(&cur[(d >> 1) - plo], 1u << sh);
      int local = (int)((old >> sh) & 0xFFFFu);
      csr_src[row_ptr[d] + local] = src[i];
    }
  }
}

// ---------------- prescale feats -> fp16 (+ weight transpose folded in) ----------------
#define WPTOT (F_IN * F_H1 + F_H1 * F_H2 + F_H2 * F_OUT)
__global__ void k_prewprep(const float* __restrict__ X, const float* __restrict__ ns,
                           __half* __restrict__ Y,
                           const float* __restrict__ W1, const float* __restrict__ W2,
                           const float* __restrict__ W3, __half* __restrict__ wt1,
                           __half* __restrict__ wt2, __half* __restrict__ wt3) {
  int i = blockIdx.x * 256 + threadIdx.x;
  if (i < NODES * 32) {   // prescale: 32 float4 per 128-col row
    int row = i >> 5;
    float s = ns[row];
    float4 v = reinterpret_cast<const float4*>(X)[i];
    __half2 h0 = __floats2half2_rn(v.x * s, v.y * s);
    __half2 h1 = __floats2half2_rn(v.z * s, v.w * s);
    union { struct { __half2 a, b; } h; uint2 u; } o;
    o.h.a = h0; o.h.b = h1;
    reinterpret_cast<uint2*>(Y)[i] = o.u;
  }
  if (i < WPTOT) {        // weight transpose -> fp16
    if (i < F_IN * F_H1) {
      int k = i >> 8, n = i & 255;
      wt1[(size_t)n * F_IN + k] = __float2half_rn(W1[i]);
    } else if (i < F_IN * F_H1 + F_H1 * F_H2) {
      int j = i - F_IN * F_H1;
      int k = j >> 8, n = j & 255;
      wt2[(size_t)n * F_H1 + k] = __float2half_rn(W2[j]);
    } else {
      int j = i - F_IN * F_H1 - F_H1 * F_H2;
      int k = j >> 6, n = j & 63;
      wt3[(size_t)n * F_H2 + k] = __float2half_rn(W3[j]);
    }
  }
}

// ---------------- fp16 gather helpers ----------------
struct u32x8s { uint4 a, b; };
template <int HPL> struct raw_t_sel;
template <> struct raw_t_sel<2> { using type = unsigned int; };
template <> struct raw_t_sel<4> { using type = uint2; };
template <> struct raw_t_sel<8> { using type = uint4; };
template <> struct raw_t_sel<16> { using type = u32x8s; };

template <int HPL>
__device__ __forceinline__ typename raw_t_sel<HPL>::type graw(const __half* p) {
  if constexpr (HPL == 16) {
    u32x8s r;
    r.a = *reinterpret_cast<const uint4*>(p);
    r.b = *reinterpret_cast<const uint4*>(p + 8);
    return r;
  } else {
    return *reinterpret_cast<const typename raw_t_sel<HPL>::type*>(p);
  }
}
__device__ __forceinline__ void acc_u32(float* acc, unsigned u) {
  union { unsigned u; __half2 h; } a; a.u = u;
  float2 f = __half22float2(a.h);
  acc[0] += f.x; acc[1] += f.y;
}
template <int HPL>
__device__ __forceinline__ void raw_acc(float* acc, typename raw_t_sel<HPL>::type r) {
  if constexpr (HPL == 16) {
    acc_u32(acc + 0, r.a.x);  acc_u32(acc + 2, r.a.y);
    acc_u32(acc + 4, r.a.z);  acc_u32(acc + 6, r.a.w);
    acc_u32(acc + 8, r.b.x);  acc_u32(acc + 10, r.b.y);
    acc_u32(acc + 12, r.b.z); acc_u32(acc + 14, r.b.w);
  } else if constexpr (HPL == 8) {
    acc_u32(acc + 0, r.x); acc_u32(acc + 2, r.y);
    acc_u32(acc + 4, r.z); acc_u32(acc + 6, r.w);
  } else if constexpr (HPL == 4) {
    acc_u32(acc + 0, r.x); acc_u32(acc + 2, r.y);
  } else {
    acc_u32(acc, r);
  }
}

// ---------------- SpMM (fp16 source): Y[v] = nd[v]*(X[v] + sum_{u->v} X[u]) (+bias)
// EPI edges per wave-iteration: lane = (sub-edge, feature-slot); butterfly
// shfl_xor combine at the end. OHALF: fp16 out, else f32.
template <int D, int EPI, bool BIAS, bool OHALF>
__global__ __launch_bounds__(256) void k_spmm_h(
    const __half* __restrict__ X, const int* __restrict__ row_ptr,
    const int* __restrict__ csr_src, const float* __restrict__ nd,
    const float* __restrict__ bias, void* __restrict__ Y, int n) {
  constexpr int LPN = 64 / EPI;    // lanes per edge-row
  constexpr int HPL = D / LPN;     // halves per lane
  static_assert(HPL >= 2 && HPL <= 16, "bad HPL");
  const int v = (blockIdx.x * blockDim.x + threadIdx.x) >> 6;
  const int lane = threadIdx.x & 63;
  if (v >= n) return;
  const int sub = lane / LPN;
  const int fl = lane % LPN;
  const int off = fl * HPL;
  const __half* __restrict__ Xo = X + off;

  float acc[HPL] = {};
  if (sub == 0) raw_acc<HPL>(acc, graw<HPL>(Xo + (size_t)v * D));   // self term

  const int beg = row_ptr[v];
  const int end = row_ptr[v + 1];
#pragma unroll 2
  for (int e = beg + sub; e < end; e += EPI) {
    int u = csr_src[e];
    raw_acc<HPL>(acc, graw<HPL>(Xo + (size_t)u * D));
  }

#pragma unroll
  for (int o = LPN; o < 64; o <<= 1)
#pragma unroll
    for (int i = 0; i < HPL; ++i) acc[i] += __shfl_xor(acc[i], o);

  if (sub != 0) return;
  const float sc = nd[v];
  float o[HPL];
#pragma unroll
  for (int i = 0; i < HPL; ++i) {
    o[i] = sc * acc[i];
    if (BIAS) o[i] += bias[off + i];
  }

  if constexpr (OHALF) {
    __half* yp = reinterpret_cast<__half*>(Y) + (size_t)v * D + off;
    if constexpr (HPL == 16) {
      union { struct { __half2 a, b, c, d; } h; uint4 u; } p0, p1;
      p0.h.a = __floats2half2_rn(o[0], o[1]);
      p0.h.b = __floats2half2_rn(o[2], o[3]);
      p0.h.c = __floats2half2_rn(o[4], o[5]);
      p0.h.d = __floats2half2_rn(o[6], o[7]);
      p1.h.a = __floats2half2_rn(o[8], o[9]);
      p1.h.b = __floats2half2_rn(o[10], o[11]);
      p1.h.c = __floats2half2_rn(o[12], o[13]);
      p1.h.d = __floats2half2_rn(o[14], o[15]);
      *reinterpret_cast<uint4*>(yp) = p0.u;
      *reinterpret_cast<uint4*>(yp + 8) = p1.u;
    } else if constexpr (HPL == 8) {
      union { struct { __half2 a, b, c, d; } h; uint4 u; } pk;
      pk.h.a = __floats2half2_rn(o[0], o[1]);
      pk.h.b = __floats2half2_rn(o[2], o[3]);
      pk.h.c = __floats2half2_rn(o[4], o[5]);
      pk.h.d = __floats2half2_rn(o[6], o[7]);
      *reinterpret_cast<uint4*>(yp) = pk.u;
    } else if constexpr (HPL == 4) {
      union { struct { __half2 a, b; } h; uint2 u; } pk;
      pk.h.a = __floats2half2_rn(o[0], o[1]);
      pk.h.b = __floats2half2_rn(o[2], o[3]);
      *reinterpret_cast<uint2*>(yp) = pk.u;
    } else {
      *reinterpret_cast<__half2*>(yp) = __floats2half2_rn(o[0], o[1]);
    }
  } else {
    float* yp = reinterpret_cast<float*>(Y) + (size_t)v * D + off;
    if constexpr (HPL == 8) {
      *reinterpret_cast<float4*>(yp) = make_float4(o[0], o[1], o[2], o[3]);
      *reinterpret_cast<float4*>(yp + 4) = make_float4(o[4], o[5], o[6], o[7]);
    } else if constexpr (HPL == 4) {
      *reinterpret_cast<float4*>(yp) = make_float4(o[0], o[1], o[2], o[3]);
    } else {
      *reinterpret_cast<float2*>(yp) = make_float2(o[0], o[1]);
    }
  }
}

// ---------------- pure-fp16 MFMA GEMM ----------------
template <int K, int NOUT, int BM, int WM, int WN, int MF, int NF,
          bool RELU, bool BIAS, bool NSOUT, bool OHALF>
__global__ __launch_bounds__(256) void k_gemm_h(
    const __half* __restrict__ A, const __half* __restrict__ Wt,
    const float* __restrict__ bias, const float* __restrict__ ns,
    void* __restrict__ C, int M) {
  constexpr int BN = WN * NF * 16;
  static_assert(BM == WM * MF * 16, "BM mismatch");
  static_assert(BN == NOUT, "BN must equal NOUT");
  static_assert((BM * 4) % 256 == 0, "staging loop divisibility");
  constexpr int LDP = 40;  // 80B row stride -> bank stride 20 -> <=2-way (free), 16B aligned

  __shared__ __half As[BM][LDP];
  __shared__ __half Ws[BN][LDP];

  const int tid = threadIdx.x;
  const int bm = blockIdx.x * BM;
  const int lane = tid & 63;
  const int wave = tid >> 6;
  const int wmi = wave / WN;
  const int wni = wave % WN;
  const int rl = lane & 15;
  const int kg = lane >> 4;       // 0..3
  const int kb = kg * 8;

  f32x4 acc[MF][NF];
#pragma unroll
  for (int m = 0; m < MF; ++m)
#pragma unroll
    for (int n = 0; n < NF; ++n) acc[m][n] = (f32x4){0.f, 0.f, 0.f, 0.f};

  for (int kk = 0; kk < K; kk += 32) {
#pragma unroll
    for (int s0 = 0; s0 < BM * 4; s0 += 256) {
      int s = s0 + tid;
      int r = s >> 2, c8 = (s & 3) << 3;
      int grow = bm + r;
      ushort8v v = (ushort8v){0, 0, 0, 0, 0, 0, 0, 0};
      if (grow < M)
        v = *reinterpret_cast<const ushort8v*>(A + (size_t)grow * K + kk + c8);
      *reinterpret_cast<ushort8v*>(&As[r][c8]) = v;
    }
#pragma unroll
    for (int s0 = 0; s0 < BN * 4; s0 += 256) {
      int s = s0 + tid;
      int nn = s >> 2, k8 = (s & 3) << 3;
      *reinterpret_cast<ushort8v*>(&Ws[nn][k8]) =
          *reinterpret_cast<const ushort8v*>(Wt + (size_t)nn * K + kk + k8);
    }
    __syncthreads();

    f16x8 af[MF], bf[NF];
#pragma unroll
    for (int m = 0; m < MF; ++m) {
      const int r = wmi * MF * 16 + m * 16 + rl;
      af[m] = *reinterpret_cast<const f16x8*>(&As[r][kb]);
    }
#pragma unroll
    for (int n = 0; n < NF; ++n) {
      const int c = wni * NF * 16 + n * 16 + rl;
      bf[n] = *reinterpret_cast<const f16x8*>(&Ws[c][kb]);
    }
#pragma unroll
    for (int m = 0; m < MF; ++m)
#pragma unroll
      for (int n = 0; n < NF; ++n)
        acc[m][n] = __builtin_amdgcn_mfma_f32_16x16x32_f16(af[m], bf[n], acc[m][n], 0, 0, 0);
    __syncthreads();
  }

#pragma unroll
  for (int m = 0; m < MF; ++m) {
#pragma unroll
    for (int n = 0; n < NF; ++n) {
      const int col = wni * NF * 16 + n * 16 + rl;
      const float bb = BIAS ? bias[col] : 0.f;
      const int rowbase = bm + wmi * MF * 16 + m * 16 + kg * 4;
#pragma unroll
      for (int i = 0; i < 4; ++i) {
        int grow = rowbase + i;
        if (grow < M) {
          float val = acc[m][n][i] + bb;
          if (RELU) val = fmaxf(val, 0.f);
          if (NSOUT) val *= ns[grow];
          if constexpr (OHALF)
            reinterpret_cast<__half*>(C)[(size_t)grow * NOUT + col] = __float2half_rn(val);
          else
            reinterpret_cast<float*>(C)[(size_t)grow * NOUT + col] = val;
        }
      }
    }
  }
}

// ---------------- launch ----------------
extern "C" void kernel_launch(void* const* d_in, const int* in_sizes, int n_in,
                              void* d_out, int out_size, void* d_ws, size_t ws_size,
                              hipStream_t stream) {
  const float* feats = (const float*)d_in[0];
  const float* W1 = (const float*)d_in[1];
  const float* b1 = (const float*)d_in[2];
  const float* W2 = (const float*)d_in[3];
  const float* b2 = (const float*)d_in[4];
  const float* W3 = (const float*)d_in[5];
  const float* b3 = (const float*)d_in[6];
  const int* src = (const int*)d_in[7];
  const int* dst = (const int*)d_in[8];
  float* out = (float*)d_out;
  const int N = NODES;
  const int E = in_sizes[7];
  const int NB = (N + 255) / 256;          // scan blocks (196 <= 256)

  char* ws = (char*)d_ws;
  size_t off = 0;
  auto alloc = [&](size_t bytes) -> void* {
    void* p = ws + off;
    off += (bytes + 255) & ~(size_t)255;
    return p;
  };
  __half* w0h = (__half*)alloc((size_t)N * 256 * sizeof(__half));  // spmm2 out
  __half* w1r = (__half*)alloc((size_t)N * 256 * sizeof(__half));  // spmm1 out / gemm2 out
  __half* w2r = (__half*)alloc((size_t)N * 256 * sizeof(__half));  // prescaled feats / gemm1 out / gemm3 out
  int* deg_in = (int*)alloc((size_t)N * sizeof(int));
  float* ns = (float*)alloc((size_t)N * sizeof(float));
  float* nd = (float*)alloc((size_t)N * sizeof(float));
  int* row_ptr = (int*)alloc((size_t)(N + 1) * sizeof(int));
  int* csr_src = (int*)alloc((size_t)E * sizeof(int));
  int* psum = (int*)alloc((size_t)NB * sizeof(int));
  unsigned* p_out = (unsigned*)alloc((size_t)SLICES * NPACK * sizeof(unsigned));
  unsigned* p_in = (unsigned*)alloc((size_t)SLICES * NPACK * sizeof(unsigned));
  unsigned* base_in = (unsigned*)alloc((size_t)SLICES * NPACK * sizeof(unsigned));
  __half* wt1 = (__half*)alloc((size_t)F_IN * F_H1 * sizeof(__half));
  __half* wt2 = (__half*)alloc((size_t)F_H1 * F_H2 * sizeof(__half));
  __half* wt3 = (__half*)alloc((size_t)F_H2 * F_OUT * sizeof(__half));
  (void)ws_size; (void)n_in; (void)out_size;

  // ---- graph preprocessing (no global atomics; round-10 proven chain) ----
  hipLaunchKernelGGL(k_hist2, dim3(SLICES * 4), dim3(512), 0, stream,
                     src, dst, p_out, p_in, E);
  hipLaunchKernelGGL(k_degnorm, dim3((NPACK + 255) / 256), dim3(256), 0, stream,
                     p_out, p_in, base_in, deg_in, ns, nd);
  hipLaunchKernelGGL(k_scan1, dim3(NB), dim3(256), 0, stream, deg_in, psum, N);
  hipLaunchKernelGGL(k_scan2, dim3(1), dim3(256), 0, stream, psum, NB);
  hipLaunchKernelGGL(k_scan3, dim3(NB), dim3(256), 0, stream, deg_in, psum, row_ptr, N);
  hipLaunchKernelGGL(k_scatter4, dim3(SLICES * 4), dim3(512), 0, stream,
                     src, dst, row_ptr, base_in, csr_src, E);

  // ---- prescale feats -> fp16 (+ weight transpose folded in) ----
  hipLaunchKernelGGL(k_prewprep, dim3((N * 32 + 255) / 256), dim3(256), 0, stream,
                     feats, ns, w2r, W1, W2, W3, wt1, wt2, wt3);

  auto grid_w = [](int waves) { return dim3((waves + 3) / 4); };  // 4 waves/block

  // ---- layer 1: SpMM(d=128, EPI=8) -> fp16; GEMM 128->256 (BM=64, +b1, relu, *ns) -> fp16
  hipLaunchKernelGGL((k_spmm_h<128, 8, false, true>), grid_w(N), dim3(256), 0, stream,
                     w2r, row_ptr, csr_src, nd, nullptr, w1r, N);
  hipLaunchKernelGGL((k_gemm_h<128, 256, 64, 1, 4, 4, 4, true, true, true, true>),
                     dim3((N + 63) / 64), dim3(256), 0, stream,
                     w1r, wt1, b1, ns, w2r, N);

  // ---- layer 2: SpMM(d=256, EPI=4) -> fp16; GEMM 256->256 (BM=64, +b2, relu, *ns) -> fp16
  hipLaunchKernelGGL((k_spmm_h<256, 4, false, true>), grid_w(N), dim3(256), 0, stream,
                     w2r, row_ptr, csr_src, nd, nullptr, w0h, N);
  hipLaunchKernelGGL((k_gemm_h<256, 256, 64, 1, 4, 4, 4, true, true, true, true>),
                     dim3((N + 63) / 64), dim3(256), 0, stream,
                     w0h, wt2, b2, ns, w1r, N);

  // ---- layer 3: GEMM 256->64 (no act) -> fp16; SpMM(d=64, EPI=8) +b3 -> out f32
  hipLaunchKernelGGL((k_gemm_h<256, 64, 128, 4, 1, 2, 4, false, false, false, true>),
                     dim3((N + 127) / 128), dim3(256), 0, stream,
                     w1r, wt3, nullptr, nullptr, w2r, N);
  hipLaunchKernelGGL((k_spmm_h<64, 8, true, false>), dim3((N + 3) / 4), dim3(256), 0, stream,
                     w2r, row_ptr, csr_src, nd, b3, out, N);
}